// Round 1
// 396.723 us; speedup vs baseline: 1.0151x; 1.0151x over previous
//
#include <hip/hip_runtime.h>
#include <math.h>

#define NN 20000
#define NE 256000
#define IN_DIM 64
#define HID 128
#define DE 289     // 2*HID + 1 + 32
#define D0 320     // IN_DIM + 2*HID
#define TILE_E 64
#define NB64 313   // ceil(NN/64)
#define NUB 8      // nodes per block (fused node kernel)
#define ECAP 512   // LDS-staged edges per block (avg ~102, Poisson tail << 512)
#define SRCMASK 0x3FFFFFFF

typedef unsigned short u16;
typedef unsigned int u32;
typedef unsigned long long u64;
typedef __attribute__((ext_vector_type(8))) short short8;
typedef __attribute__((ext_vector_type(4))) float float4v;

// Bpack layout offsets (u16 elements)
#define OFF_WE   0          // 3 x 40960 (K=289 pad 320, N=128) — tiles 0..3 = We rows 0..255
#define OFF_W0   122880     // 40960 (K=320, N=128)
#define OFF_W1   163840     // 16384 (K=128, N=128)
#define OFF_W2   180224     // 16384
#define OFF_WH   196608     // 3 x 32768 (K=256, N=128)
#define OFF_H2I  294912     // 8192 (K=128, N=64)
#define PACK_TOT 303104

static __device__ __forceinline__ u16 f2bf(float f) {
    unsigned int u = __float_as_uint(f);
    u += 0x7fffu + ((u >> 16) & 1u);
    return (u16)(u >> 16);
}
static __device__ __forceinline__ float bf2f(u16 s) {
    return __uint_as_float(((unsigned int)s) << 16);
}
static __device__ __forceinline__ float bflo(u32 u) { return bf2f((u16)(u & 0xffffu)); }
static __device__ __forceinline__ float bfhi(u32 u) { return bf2f((u16)(u >> 16)); }
static __device__ __forceinline__ u32 pack2(float a, float b) {
    return (u32)f2bf(a) | ((u32)f2bf(b) << 16);
}
static __device__ __forceinline__ uint4 pack8(const float* v) {
    uint4 r;
    r.x = (u32)f2bf(v[0]) | ((u32)f2bf(v[1]) << 16);
    r.y = (u32)f2bf(v[2]) | ((u32)f2bf(v[3]) << 16);
    r.z = (u32)f2bf(v[4]) | ((u32)f2bf(v[5]) << 16);
    r.w = (u32)f2bf(v[6]) | ((u32)f2bf(v[7]) << 16);
    return r;
}
static __device__ __forceinline__ void unpack8(uint4 a, float* o) {
    o[0]=bflo(a.x); o[1]=bfhi(a.x); o[2]=bflo(a.y); o[3]=bfhi(a.y);
    o[4]=bflo(a.z); o[5]=bfhi(a.z); o[6]=bflo(a.w); o[7]=bfhi(a.w);
}
static __device__ __forceinline__ float silu(float v) {
    return v * (1.f / (1.f + __expf(-v)));
}

// ================= CSR build =================
__global__ __launch_bounds__(256) void hist_kernel(
    const float* __restrict__ X_t, const int* __restrict__ edges,
    float* __restrict__ x, int* __restrict__ deg)
{
    int gid = blockIdx.x * blockDim.x + threadIdx.x;
    int stride = gridDim.x * blockDim.x;
    for (int i = gid; i < NN * 3; i += stride) x[i] = X_t[i];
    for (int e = gid; e < NE; e += stride)
        atomicAdd(&deg[edges[NE + e]], 1);
}

__global__ __launch_bounds__(256) void scan_kernel(
    const int* __restrict__ deg, int* __restrict__ row_start, int* __restrict__ head)
{
    __shared__ int s[256];
    int tx = threadIdx.x;
    const int per = (NN + 255) / 256;
    int st = tx * per, en = st + per;
    if (st > NN) st = NN;
    if (en > NN) en = NN;
    int sum = 0;
    for (int i = st; i < en; ++i) sum += deg[i];
    s[tx] = sum;
    __syncthreads();
    for (int off = 1; off < 256; off <<= 1) {
        int t = (tx >= off) ? s[tx - off] : 0;
        __syncthreads();
        s[tx] += t;
        __syncthreads();
    }
    int run = (tx == 0) ? 0 : s[tx - 1];
    for (int i = st; i < en; ++i) {
        row_start[i] = run; head[i] = run; run += deg[i];
    }
    if (tx == 255) row_start[NN] = run;
}

// permute edges into dst-sorted order; pack etype into src bit 30
__global__ __launch_bounds__(256) void scatter_kernel(
    const int* __restrict__ edges, const int* __restrict__ etype,
    int* __restrict__ head,
    int* __restrict__ src_s, int* __restrict__ dst_s)
{
    int gid = blockIdx.x * blockDim.x + threadIdx.x;
    int stride = gridDim.x * blockDim.x;
    for (int e = gid; e < NE; e += stride) {
        int d = edges[NE + e];
        int p = atomicAdd(&head[d], 1);
        src_s[p] = edges[e] | (etype[e] << 30);
        dst_s[p] = d;
    }
}

// ================= weight frag-order packing =================
__global__ __launch_bounds__(256) void pack_all_kernel(
    const float* __restrict__ We, const float* __restrict__ W0,
    const float* __restrict__ W1, const float* __restrict__ W2,
    const float* __restrict__ Wh, const float* __restrict__ h2i,
    u16* __restrict__ Bp)
{
    int idx = blockIdx.x * 256 + threadIdx.x;
    if (idx >= PACK_TOT) return;
    const float* src; int N = 128, Ksrc; int r;
    if (idx < OFF_W0) {
        int layer = idx / 40960; r = idx - layer * 40960;
        src = We + (size_t)layer * DE * HID; Ksrc = DE;
    } else if (idx < OFF_W1) { r = idx - OFF_W0; src = W0; Ksrc = 320; }
    else if (idx < OFF_W2)   { r = idx - OFF_W1; src = W1; Ksrc = 128; }
    else if (idx < OFF_WH)   { r = idx - OFF_W2; src = W2; Ksrc = 128; }
    else if (idx < OFF_H2I) {
        int t = idx - OFF_WH; int layer = t / 32768; r = t - layer * 32768;
        src = Wh + (size_t)layer * 256 * HID; Ksrc = 256;
    } else { r = idx - OFF_H2I; src = h2i; Ksrc = 128; N = 64; }
    int ntc = N / 16;
    int j = r & 7, lane = (r >> 3) & 63;
    int rem = r >> 9;
    int nt = rem % ntc, ks = rem / ntc;
    int k = ks * 32 + ((lane >> 4) << 3) + j;
    int c = nt * 16 + (lane & 15);
    Bp[idx] = f2bf((k < Ksrc) ? src[(size_t)k * N + c] : 0.f);
}

// ================= edge tail precompute (f32) =================
__global__ __launch_bounds__(256) void precomp_tv_kernel(
    const float* __restrict__ edge_table, const float* __restrict__ We,
    const float* __restrict__ be, float* __restrict__ tv, float* __restrict__ wed2)
{
    int idx = blockIdx.x * 256 + threadIdx.x;
    if (idx < 768) {
        int f = idx & 127, t = (idx >> 7) & 1, l = idx >> 8;
        float acc = be[l * 128 + f];
        const float* W = We + (size_t)l * DE * HID;
        #pragma unroll
        for (int k = 0; k < 32; ++k)
            acc += edge_table[t * 32 + k] * W[(size_t)(257 + k) * HID + f];
        tv[l * 256 + t * 128 + f] = acc;
    } else if (idx < 1152) {
        int r = idx - 768;
        int f = r & 127, l = r >> 7;
        wed2[l * 128 + f] = We[(size_t)l * DE * HID + (size_t)256 * HID + f];
    }
}

// ================= node MLP: MFMA, 64 nodes/block =================
__global__ __launch_bounds__(256) void node_mlp_mfma_kernel(
    const float* __restrict__ H_t, const float* __restrict__ cond,
    const float* __restrict__ t_in,
    const u16* __restrict__ W0p, const float* __restrict__ b0,
    const u16* __restrict__ W1p, const float* __restrict__ b1,
    const u16* __restrict__ W2p, const float* __restrict__ b2,
    float* __restrict__ h, u16* __restrict__ h_bf)
{
    __shared__ u16 s_A[64 * 64];
    __shared__ u16 s_B[64 * 128];
    __shared__ u16 s_h[64 * 128];
    __shared__ float s_t[64];

    int tx = threadIdx.x;
    int n0 = blockIdx.x * 64;
    int l = tx & 63, w = tx >> 6;
    int mt_base = (w & 1) * 2, nt_base = (w >> 1) * 4;
    const float cfr = -logf(10000.f) / 63.f;

    if (tx < 64) s_t[tx] = (n0 + tx < NN) ? t_in[n0 + tx] : 0.f;

    float4v acc[2][4];
    #pragma unroll
    for (int mi = 0; mi < 2; ++mi)
        #pragma unroll
        for (int ni = 0; ni < 4; ++ni) acc[mi][ni] = (float4v){0.f,0.f,0.f,0.f};

    for (int t = 0; t < 5; ++t) {
        __syncthreads();
        #pragma unroll
        for (int it = 0; it < 2; ++it) {
            int flat = it * 256 + tx;
            int n = flat >> 3, sl = flat & 7;
            int c = sl ^ (n & 7);
            int k0 = t * 64 + c * 8;
            float tv8[8];
            int gn = n0 + n;
            if (gn < NN) {
                if (k0 < 192) {
                    const float* src = (k0 < 64) ? &H_t[(size_t)gn * IN_DIM + k0]
                                                 : &cond[(size_t)gn * HID + (k0 - 64)];
                    float4 a = *(const float4*)src;
                    float4 b = *(const float4*)(src + 4);
                    tv8[0]=a.x; tv8[1]=a.y; tv8[2]=a.z; tv8[3]=a.w;
                    tv8[4]=b.x; tv8[5]=b.y; tv8[6]=b.z; tv8[7]=b.w;
                } else {
                    float tv = s_t[n];
                    int jj = (k0 - 192) & 63;
                    bool is_sin = (k0 < 256);
                    #pragma unroll
                    for (int jx = 0; jx < 8; ++jx) {
                        float ang = tv * __expf(cfr * (float)(jj + jx));
                        tv8[jx] = is_sin ? __sinf(ang) : __cosf(ang);
                    }
                }
            } else {
                #pragma unroll
                for (int jx = 0; jx < 8; ++jx) tv8[jx] = 0.f;
            }
            *(uint4*)&s_A[n * 64 + sl * 8] = pack8(tv8);
        }
        #pragma unroll
        for (int it = 0; it < 4; ++it) {
            int flat = it * 256 + tx;
            ((uint4*)s_B)[flat] = ((const uint4*)(W0p + (size_t)t * 8192))[flat];
        }
        __syncthreads();
        #pragma unroll
        for (int s = 0; s < 2; ++s) {
            short8 af[2], bfv[4];
            #pragma unroll
            for (int mi = 0; mi < 2; ++mi) {
                int m = (mt_base + mi) * 16 + (l & 15);
                int c = s * 4 + (l >> 4);
                int slot = c ^ (l & 7);
                af[mi] = *(const short8*)(s_A + m * 64 + slot * 8);
            }
            #pragma unroll
            for (int ni = 0; ni < 4; ++ni)
                bfv[ni] = *(const short8*)(s_B + ((s * 8 + nt_base + ni) * 64 + l) * 8);
            #pragma unroll
            for (int mi = 0; mi < 2; ++mi)
                #pragma unroll
                for (int ni = 0; ni < 4; ++ni)
                    acc[mi][ni] = __builtin_amdgcn_mfma_f32_16x16x32_bf16(
                        af[mi], bfv[ni], acc[mi][ni], 0, 0, 0);
        }
    }
    #pragma unroll
    for (int mi = 0; mi < 2; ++mi) {
        #pragma unroll
        for (int ni = 0; ni < 4; ++ni) {
            int f = (nt_base + ni) * 16 + (l & 15);
            float bv = b0[f];
            #pragma unroll
            for (int r = 0; r < 4; ++r) {
                int m = (mt_base + mi) * 16 + (l >> 4) * 4 + r;
                float v = fmaxf(acc[mi][ni][r] + bv, 0.f);
                int slot = (f >> 3) ^ (m & 7);
                s_h[m * 128 + slot * 8 + (f & 7)] = f2bf(v);
            }
            acc[mi][ni] = (float4v){0.f,0.f,0.f,0.f};
        }
    }
    for (int t = 0; t < 2; ++t) {
        __syncthreads();
        #pragma unroll
        for (int it = 0; it < 4; ++it) {
            int flat = it * 256 + tx;
            ((uint4*)s_B)[flat] = ((const uint4*)(W1p + (size_t)t * 8192))[flat];
        }
        __syncthreads();
        #pragma unroll
        for (int s = 0; s < 2; ++s) {
            short8 af[2], bfv[4];
            #pragma unroll
            for (int mi = 0; mi < 2; ++mi) {
                int m = (mt_base + mi) * 16 + (l & 15);
                int c = t * 8 + s * 4 + (l >> 4);
                int slot = c ^ (l & 7);
                af[mi] = *(const short8*)(s_h + m * 128 + slot * 8);
            }
            #pragma unroll
            for (int ni = 0; ni < 4; ++ni)
                bfv[ni] = *(const short8*)(s_B + ((s * 8 + nt_base + ni) * 64 + l) * 8);
            #pragma unroll
            for (int mi = 0; mi < 2; ++mi)
                #pragma unroll
                for (int ni = 0; ni < 4; ++ni)
                    acc[mi][ni] = __builtin_amdgcn_mfma_f32_16x16x32_bf16(
                        af[mi], bfv[ni], acc[mi][ni], 0, 0, 0);
        }
    }
    __syncthreads();
    #pragma unroll
    for (int mi = 0; mi < 2; ++mi) {
        #pragma unroll
        for (int ni = 0; ni < 4; ++ni) {
            int f = (nt_base + ni) * 16 + (l & 15);
            float bv = b1[f];
            #pragma unroll
            for (int r = 0; r < 4; ++r) {
                int m = (mt_base + mi) * 16 + (l >> 4) * 4 + r;
                float v = fmaxf(acc[mi][ni][r] + bv, 0.f);
                int slot = (f >> 3) ^ (m & 7);
                s_h[m * 128 + slot * 8 + (f & 7)] = f2bf(v);
            }
            acc[mi][ni] = (float4v){0.f,0.f,0.f,0.f};
        }
    }
    for (int t = 0; t < 2; ++t) {
        __syncthreads();
        #pragma unroll
        for (int it = 0; it < 4; ++it) {
            int flat = it * 256 + tx;
            ((uint4*)s_B)[flat] = ((const uint4*)(W2p + (size_t)t * 8192))[flat];
        }
        __syncthreads();
        #pragma unroll
        for (int s = 0; s < 2; ++s) {
            short8 af[2], bfv[4];
            #pragma unroll
            for (int mi = 0; mi < 2; ++mi) {
                int m = (mt_base + mi) * 16 + (l & 15);
                int c = t * 8 + s * 4 + (l >> 4);
                int slot = c ^ (l & 7);
                af[mi] = *(const short8*)(s_h + m * 128 + slot * 8);
            }
            #pragma unroll
            for (int ni = 0; ni < 4; ++ni)
                bfv[ni] = *(const short8*)(s_B + ((s * 8 + nt_base + ni) * 64 + l) * 8);
            #pragma unroll
            for (int mi = 0; mi < 2; ++mi)
                #pragma unroll
                for (int ni = 0; ni < 4; ++ni)
                    acc[mi][ni] = __builtin_amdgcn_mfma_f32_16x16x32_bf16(
                        af[mi], bfv[ni], acc[mi][ni], 0, 0, 0);
        }
    }
    #pragma unroll
    for (int mi = 0; mi < 2; ++mi) {
        #pragma unroll
        for (int ni = 0; ni < 4; ++ni) {
            int f = (nt_base + ni) * 16 + (l & 15);
            float bv = b2[f];
            #pragma unroll
            for (int r = 0; r < 4; ++r) {
                int m = (mt_base + mi) * 16 + (l >> 4) * 4 + r;
                int gn = n0 + m;
                if (gn < NN) {
                    float v = acc[mi][ni][r] + bv;
                    h[(size_t)gn * HID + f] = v;
                    h_bf[(size_t)gn * HID + f] = f2bf(v);
                }
            }
        }
    }
}

// ================= cvec: C[n][0:128]=h@We_src, C[n][128:256]=h@We_dst (bf16 out) =================
__global__ __launch_bounds__(256) void cvec_kernel(
    const u16* __restrict__ h_bf, const u16* __restrict__ WEp,
    u16* __restrict__ Cbf)
{
    __shared__ u16 s_A[64 * 64];
    __shared__ u16 s_B[64 * 128];

    int tx = threadIdx.x;
    int n0 = blockIdx.x * 64;
    int l = tx & 63, w = tx >> 6;
    int mt_base = (w & 1) * 2, nt_base = (w >> 1) * 4;

    float4v acc[2][2][4];  // [side][mi][ni]
    #pragma unroll
    for (int sd = 0; sd < 2; ++sd)
        #pragma unroll
        for (int mi = 0; mi < 2; ++mi)
            #pragma unroll
            for (int ni = 0; ni < 4; ++ni)
                acc[sd][mi][ni] = (float4v){0.f,0.f,0.f,0.f};

    for (int t = 0; t < 4; ++t) {
        __syncthreads();
        #pragma unroll
        for (int it = 0; it < 2; ++it) {
            int flat = it * 256 + tx;
            int n = flat >> 3, sl = flat & 7;
            int c = sl ^ (n & 7);
            int gn = n0 + n;
            uint4 v = make_uint4(0,0,0,0);
            if (gn < NN) v = *(const uint4*)(h_bf + (size_t)gn * 128 + (t & 1) * 64 + c * 8);
            *(uint4*)&s_A[n * 64 + sl * 8] = v;
        }
        #pragma unroll
        for (int it = 0; it < 4; ++it) {
            int flat = it * 256 + tx;
            ((uint4*)s_B)[flat] = ((const uint4*)(WEp + (size_t)t * 8192))[flat];
        }
        __syncthreads();
        int sd = t >> 1;
        #pragma unroll
        for (int s = 0; s < 2; ++s) {
            short8 af[2], bfv[4];
            #pragma unroll
            for (int mi = 0; mi < 2; ++mi) {
                int m = (mt_base + mi) * 16 + (l & 15);
                int c = s * 4 + (l >> 4);
                int slot = c ^ (l & 7);
                af[mi] = *(const short8*)(s_A + m * 64 + slot * 8);
            }
            #pragma unroll
            for (int ni = 0; ni < 4; ++ni)
                bfv[ni] = *(const short8*)(s_B + ((s * 8 + nt_base + ni) * 64 + l) * 8);
            #pragma unroll
            for (int mi = 0; mi < 2; ++mi)
                #pragma unroll
                for (int ni = 0; ni < 4; ++ni)
                    acc[sd][mi][ni] = __builtin_amdgcn_mfma_f32_16x16x32_bf16(
                        af[mi], bfv[ni], acc[sd][mi][ni], 0, 0, 0);
        }
    }
    #pragma unroll
    for (int sd = 0; sd < 2; ++sd) {
        #pragma unroll
        for (int mi = 0; mi < 2; ++mi) {
            #pragma unroll
            for (int ni = 0; ni < 4; ++ni) {
                int f = sd * 128 + (nt_base + ni) * 16 + (l & 15);
                #pragma unroll
                for (int r = 0; r < 4; ++r) {
                    int m = (mt_base + mi) * 16 + (l >> 4) * 4 + r;
                    int gn = n0 + m;
                    if (gn < NN)
                        Cbf[(size_t)gn * 256 + f] = f2bf(acc[sd][mi][ni][r]);
                }
            }
        }
    }
}

// ================= fused node update v4 =================
// NUB=8 nodes/block, 512 thr. One wave per node: 32 feat-chunks (4 feats) x 2 edge parities.
// - src indices + geometry staged in LDS (geom computed in-kernel from x ping-pong: no geom_kernel)
// - branchless 2-slot software-pipelined Cbf gather (2 in flight, no rotation movs)
// - Wh B-fragments read directly from L2 (zero reuse per block -> LDS staging removed; 3 barriers total)
__global__ __launch_bounds__(512, 4) void node_fused_kernel(
    float* __restrict__ h, u16* __restrict__ h_bf,
    const float* __restrict__ x_in, float* __restrict__ x_out,
    const u16* __restrict__ Cbf,
    const int* __restrict__ src_s, const int* __restrict__ dst_s,
    const int* __restrict__ row_start,
    const float* __restrict__ tv_l, const float* __restrict__ wed2_l,
    const float* __restrict__ Wx_l, const float* __restrict__ bx_l,
    const u16* __restrict__ Whp_l, const float* __restrict__ bh_l)
{
    __shared__ u16 s_A[16 * 256];      // 8 KB: rows 0..7 = [h | agg] xor-swizzled, rows 8..15 zero
    __shared__ int s_sidx[ECAP];       // 2 KB
    __shared__ float4 s_geom[ECAP];    // 8 KB: (dx,dy,dz,d2)
    __shared__ int s_rs[NUB + 1];

    int tx = threadIdx.x;
    int n0 = blockIdx.x * NUB;
    int l = tx & 63, w = tx >> 6;      // 8 waves; wave w owns node i = w
    int i = w;
    int gn = n0 + i;
    int p = l & 31, q = l >> 5;        // feat-chunk (4 feats), edge parity

    if (tx < NUB + 1) s_rs[tx] = row_start[n0 + tx];

    // ---- stage h rows (0..7) + zero rows 8..15 (chunks 0..15) ----
    if (tx < 256) {
        int n = tx >> 4, c = tx & 15;
        int slot = c ^ (n & 7);
        uint4 v = make_uint4(0, 0, 0, 0);
        if (n < NUB) v = *(const uint4*)(h_bf + (size_t)(n0 + n) * 128 + c * 8);
        *(uint4*)&s_A[n * 256 + slot * 8] = v;
    } else if (tx < 384) {
        // zero agg-chunks (16..31) of pad rows 8..15 so GEMM reads clean zeros
        int n = 8 + ((tx - 256) >> 4), c = 16 + (tx & 15);
        int slot = c ^ (n & 7);
        *(uint4*)&s_A[n * 256 + slot * 8] = make_uint4(0, 0, 0, 0);
    }

    // ---- stage edges: src|etype and fused geometry (x is L2-resident, 240 KB) ----
    int rs0 = row_start[n0];                       // uniform
    int ecnt = row_start[n0 + NUB] - rs0;          // uniform
    int ecl = ecnt < ECAP ? ecnt : ECAP;
    for (int k = tx; k < ecl; k += 512) {
        int sp = src_s[rs0 + k];
        int dn = dst_s[rs0 + k];
        s_sidx[k] = sp;
        int sm = sp & SRCMASK;
        float dx = x_in[sm * 3 + 0] - x_in[dn * 3 + 0];
        float dy = x_in[sm * 3 + 1] - x_in[dn * 3 + 1];
        float dz = x_in[sm * 3 + 2] - x_in[dn * 3 + 2];
        s_geom[k] = make_float4(dx, dy, dz, dx * dx + dy * dy + dz * dz);
    }

    // ---- per-thread constants (4 feats) ----
    float c0[4], d01[4], wed[4], wx[4];
    {
        uint2 cd = *(const uint2*)(Cbf + (size_t)gn * 256 + 128 + p * 4);
        float cdv0 = bflo(cd.x), cdv1 = bfhi(cd.x), cdv2 = bflo(cd.y), cdv3 = bfhi(cd.y);
        float4 t0 = *(const float4*)(tv_l + p * 4);
        float4 t1 = *(const float4*)(tv_l + 128 + p * 4);
        float4 wd = *(const float4*)(wed2_l + p * 4);
        float4 wv = *(const float4*)(Wx_l + p * 4);
        c0[0] = t0.x + cdv0; c0[1] = t0.y + cdv1; c0[2] = t0.z + cdv2; c0[3] = t0.w + cdv3;
        d01[0] = t1.x - t0.x; d01[1] = t1.y - t0.y; d01[2] = t1.z - t0.z; d01[3] = t1.w - t0.w;
        wed[0] = wd.x; wed[1] = wd.y; wed[2] = wd.z; wed[3] = wd.w;
        wx[0] = wv.x; wx[1] = wv.y; wx[2] = wv.z; wx[3] = wv.w;
    }
    float bx32 = bx_l[0] * (1.f / 32.f);

    __syncthreads();

    // ---- fused message + aggregation ----
    float ag[4] = {0.f, 0.f, 0.f, 0.f};
    float sx = 0.f, sy = 0.f, sz = 0.f;

    auto PROC = [&](uint2 cc, float4 gg, float ee) {
        float av[4];
        av[0] = bflo(cc.x); av[1] = bfhi(cc.x);
        av[2] = bflo(cc.y); av[3] = bfhi(cc.y);
        float wpart = bx32;
        #pragma unroll
        for (int f = 0; f < 4; ++f) {
            float t = __fmaf_rn(gg.w, wed[f], c0[f]);
            t = __fmaf_rn(ee, d01[f], t);
            float v = av[f] + t;
            float m = silu(v);
            ag[f] += m;
            wpart = __fmaf_rn(m, wx[f], wpart);
        }
        sx = __fmaf_rn(gg.x, wpart, sx);
        sy = __fmaf_rn(gg.y, wpart, sy);
        sz = __fmaf_rn(gg.z, wpart, sz);
    };

    int rs = s_rs[i], re = s_rs[i + 1];
    int eclN = re - rs0; if (eclN > ECAP) eclN = ECAP;   // per-node LDS-resident bound
    {
        int ljA = (rs - rs0) + q;        // stride-2 per parity
        int ljB = ljA + 2;
        bool hA = ljA < eclN, hB = ljB < eclN;
        int sA0 = hA ? s_sidx[ljA] : 0;
        int sB0 = hB ? s_sidx[ljB] : 0;
        float4 gA = s_geom[hA ? ljA : 0];
        float4 gB = s_geom[hB ? ljB : 0];
        uint2 cA = *(const uint2*)(Cbf + (size_t)(sA0 & SRCMASK) * 256 + p * 4);
        uint2 cB = *(const uint2*)(Cbf + (size_t)(sB0 & SRCMASK) * 256 + p * 4);
        float eA = (float)((u32)sA0 >> 30);
        float eB = (float)((u32)sB0 >> 30);
        while (hA) {
            // refill slot A (2 iterations ahead) before consuming it
            int ljC = ljA + 4; bool hC = ljC < eclN;
            int sC = hC ? s_sidx[ljC] : 0;
            float4 gC = s_geom[hC ? ljC : 0];
            uint2 cC = *(const uint2*)(Cbf + (size_t)(sC & SRCMASK) * 256 + p * 4);
            PROC(cA, gA, eA);
            cA = cC; gA = gC; eA = (float)((u32)sC >> 30); hA = hC; ljA = ljC;
            if (!hB) break;
            int ljD = ljB + 4; bool hD = ljD < eclN;
            int sD = hD ? s_sidx[ljD] : 0;
            float4 gD = s_geom[hD ? ljD : 0];
            uint2 cD = *(const uint2*)(Cbf + (size_t)(sD & SRCMASK) * 256 + p * 4);
            PROC(cB, gB, eB);
            cB = cD; gB = gD; eB = (float)((u32)sD >> 30); hB = hD; ljB = ljD;
        }
    }

    // ---- overflow tail (block had > ECAP edges; essentially never taken) ----
    if (re - rs0 > ECAP) {
        int j0 = rs0 + ECAP;
        int jstart = rs + q;
        if (jstart < j0) jstart = j0 + ((rs + q - j0) & 1);
        float xdx = x_in[gn * 3 + 0], xdy = x_in[gn * 3 + 1], xdz = x_in[gn * 3 + 2];
        for (int j = jstart; j < re; j += 2) {
            int s = src_s[j];
            int sm = s & SRCMASK;
            float dx = x_in[sm * 3 + 0] - xdx;
            float dy = x_in[sm * 3 + 1] - xdy;
            float dz = x_in[sm * 3 + 2] - xdz;
            float4 g = make_float4(dx, dy, dz, dx * dx + dy * dy + dz * dz);
            uint2 c = *(const uint2*)(Cbf + (size_t)sm * 256 + p * 4);
            PROC(c, g, (float)((u32)s >> 30));
        }
    }

    // ---- reductions (all within this node's single wave) ----
    #pragma unroll
    for (int f = 0; f < 4; ++f) ag[f] += __shfl_xor(ag[f], 32);   // combine parities
    #pragma unroll
    for (int off = 1; off <= 32; off <<= 1) {
        sx += __shfl_xor(sx, off);
        sy += __shfl_xor(sy, off);
        sz += __shfl_xor(sz, off);
    }
    if (l < 32) {
        int c2 = 16 + (p >> 1);
        int slot = c2 ^ (i & 7);
        uint2 o;
        o.x = pack2(ag[0], ag[1]);
        o.y = pack2(ag[2], ag[3]);
        *(uint2*)&s_A[i * 256 + slot * 8 + (p & 1) * 4] = o;
        if (l == 0) {
            float inv = 1.f / ((float)(re - rs) + 1.f);
            x_out[gn * 3 + 0] = x_in[gn * 3 + 0] + sx * inv;
            x_out[gn * 3 + 1] = x_in[gn * 3 + 1] + sy * inv;
            x_out[gn * 3 + 2] = x_in[gn * 3 + 2] + sz * inv;
        }
    }

    __syncthreads();

    // ---- Wh GEMM: wave w = N-tile w; B fragments straight from L2 (read-once, no reuse) ----
    float4v acc = (float4v){0.f, 0.f, 0.f, 0.f};
    #pragma unroll
    for (int t = 0; t < 4; ++t) {
        #pragma unroll
        for (int s = 0; s < 2; ++s) {
            int m = l & 15;
            int c = t * 8 + s * 4 + (l >> 4);
            int slot = c ^ (l & 7);
            short8 af = *(const short8*)(s_A + m * 256 + slot * 8);
            short8 bfv = *(const short8*)(Whp_l + (size_t)t * 8192 + ((s * 8 + w) * 64 + l) * 8);
            acc = __builtin_amdgcn_mfma_f32_16x16x32_bf16(af, bfv, acc, 0, 0, 0);
        }
    }
    // epilogue: h += silu(acc + bh)  (only rows 0..7 are real nodes)
    {
        int f = w * 16 + (l & 15);
        float bv = bh_l[f];
        #pragma unroll
        for (int r = 0; r < 4; ++r) {
            int m = (l >> 4) * 4 + r;
            if (m < NUB) {
                int gn2 = n0 + m;
                float v = acc[r] + bv;
                float hn = h[(size_t)gn2 * HID + f] + silu(v);
                h[(size_t)gn2 * HID + f] = hn;
                h_bf[(size_t)gn2 * HID + f] = f2bf(hn);
            }
        }
    }
}

// ================= final: MFMA h2i, 64 nodes/block =================
__global__ __launch_bounds__(256) void final_mfma_kernel(
    const u16* __restrict__ h_bf, const float* __restrict__ x,
    const int* __restrict__ gmask,
    const u16* __restrict__ h2ip, const float* __restrict__ b,
    float* __restrict__ out)
{
    __shared__ u16 s_A[64 * 128];
    __shared__ u16 s_B[4096];

    int tx = threadIdx.x;
    int n0 = blockIdx.x * 64;
    int l = tx & 63, w = tx >> 6;
    int mt_base = (w & 1) * 2, nt_base = (w >> 1) * 2;

    #pragma unroll
    for (int it = 0; it < 4; ++it) {
        int flat = it * 256 + tx;
        int n = flat >> 4, c = flat & 15;
        int slot = c ^ (n & 7);
        int gn = n0 + n;
        uint4 v = make_uint4(0,0,0,0);
        if (gn < NN) v = *(const uint4*)(h_bf + (size_t)gn * 128 + c * 8);
        *(uint4*)&s_A[n * 128 + slot * 8] = v;
    }

    float4v acc[2][2];
    #pragma unroll
    for (int mi = 0; mi < 2; ++mi)
        #pragma unroll
        for (int ni = 0; ni < 2; ++ni) acc[mi][ni] = (float4v){0.f,0.f,0.f,0.f};

    for (int t = 0; t < 2; ++t) {
        __syncthreads();
        #pragma unroll
        for (int it = 0; it < 2; ++it) {
            int flat = it * 256 + tx;
            ((uint4*)s_B)[flat] = ((const uint4*)(h2ip + (size_t)t * 4096))[flat];
        }
        __syncthreads();
        #pragma unroll
        for (int s = 0; s < 2; ++s) {
            short8 af[2], bfv[2];
            #pragma unroll
            for (int mi = 0; mi < 2; ++mi) {
                int m = (mt_base + mi) * 16 + (l & 15);
                int c = t * 8 + s * 4 + (l >> 4);
                int slot = c ^ (l & 7);
                af[mi] = *(const short8*)(s_A + m * 128 + slot * 8);
            }
            #pragma unroll
            for (int ni = 0; ni < 2; ++ni)
                bfv[ni] = *(const short8*)(s_B + ((s * 4 + nt_base + ni) * 64 + l) * 8);
            #pragma unroll
            for (int mi = 0; mi < 2; ++mi)
                #pragma unroll
                for (int ni = 0; ni < 2; ++ni)
                    acc[mi][ni] = __builtin_amdgcn_mfma_f32_16x16x32_bf16(
                        af[mi], bfv[ni], acc[mi][ni], 0, 0, 0);
        }
    }
    #pragma unroll
    for (int mi = 0; mi < 2; ++mi) {
        #pragma unroll
        for (int ni = 0; ni < 2; ++ni) {
            int f = (nt_base + ni) * 16 + (l & 15);
            float bv = b[f];
            #pragma unroll
            for (int r = 0; r < 4; ++r) {
                int m = (mt_base + mi) * 16 + (l >> 4) * 4 + r;
                int gn = n0 + m;
                if (gn < NN)
                    out[(size_t)gn * IN_DIM + f] = gmask[gn] ? (acc[mi][ni][r] + bv) : 0.f;
            }
        }
    }
    if (tx < 192) {
        int i = tx / 3, c = tx % 3;
        int gn = n0 + i;
        if (gn < NN)
            out[(size_t)NN * IN_DIM + gn * 3 + c] = gmask[gn] ? x[gn * 3 + c] : 0.f;
    }
}

// ================= fallback path (atomic, scalar; used only if ws too small) =================
__global__ __launch_bounds__(256) void init_fb_kernel(
    const float* __restrict__ X_t, const int* __restrict__ edges,
    float* __restrict__ x, float* __restrict__ cnt)
{
    int gid = blockIdx.x * blockDim.x + threadIdx.x;
    int stride = gridDim.x * blockDim.x;
    for (int i = gid; i < NN * 3; i += stride) x[i] = X_t[i];
    for (int e = gid; e < NE; e += stride)
        atomicAdd(&cnt[edges[NE + e]], 1.0f);
}

__global__ __launch_bounds__(128) void node_mlp_kernel(
    const float* __restrict__ H_t, const float* __restrict__ cond,
    const float* __restrict__ t_in,
    const float* __restrict__ W0, const float* __restrict__ b0,
    const float* __restrict__ W1, const float* __restrict__ b1,
    const float* __restrict__ W2, const float* __restrict__ b2,
    float* __restrict__ h)
{
    __shared__ float s_feat[D0][20];
    __shared__ float s_h0[HID][20];
    __shared__ float s_h1[HID][20];
    int n0 = blockIdx.x * 16;
    int tx = threadIdx.x;

    for (int idx = tx; idx < 16 * IN_DIM; idx += 128) {
        int i = idx >> 6, k = idx & 63;
        s_feat[k][i] = H_t[(n0 + i) * IN_DIM + k];
    }
    for (int idx = tx; idx < 16 * HID; idx += 128) {
        int i = idx >> 7, k = idx & 127;
        s_feat[IN_DIM + k][i] = cond[(n0 + i) * HID + k];
    }
    const float cfr = -logf(10000.f) / 63.f;
    for (int idx = tx; idx < 16 * HID; idx += 128) {
        int i = idx >> 7, k = idx & 127;
        float tv = t_in[n0 + i];
        int jj = k & 63;
        float ang = tv * __expf(cfr * (float)jj);
        s_feat[IN_DIM + HID + k][i] = (k < 64) ? __sinf(ang) : __cosf(ang);
    }
    __syncthreads();

    float acc[16];
    {
        float bv = b0[tx];
        #pragma unroll
        for (int i = 0; i < 16; ++i) acc[i] = bv;
        for (int k = 0; k < D0; ++k) {
            float w = W0[k * HID + tx];
            float4 f0 = *(const float4*)&s_feat[k][0];
            float4 f1 = *(const float4*)&s_feat[k][4];
            float4 f2 = *(const float4*)&s_feat[k][8];
            float4 f3 = *(const float4*)&s_feat[k][12];
            acc[0] += f0.x*w; acc[1] += f0.y*w; acc[2] += f0.z*w; acc[3] += f0.w*w;
            acc[4] += f1.x*w; acc[5] += f1.y*w; acc[6] += f1.z*w; acc[7] += f1.w*w;
            acc[8] += f2.x*w; acc[9] += f2.y*w; acc[10]+= f2.z*w; acc[11]+= f2.w*w;
            acc[12]+= f3.x*w; acc[13]+= f3.y*w; acc[14]+= f3.z*w; acc[15]+= f3.w*w;
        }
        #pragma unroll
        for (int i = 0; i < 16; ++i) s_h0[tx][i] = fmaxf(acc[i], 0.f);
    }
    __syncthreads();
    {
        float bv = b1[tx];
        #pragma unroll
        for (int i = 0; i < 16; ++i) acc[i] = bv;
        for (int k = 0; k < HID; ++k) {
            float w = W1[k * HID + tx];
            float4 f0 = *(const float4*)&s_h0[k][0];
            float4 f1 = *(const float4*)&s_h0[k][4];
            float4 f2 = *(const float4*)&s_h0[k][8];
            float4 f3 = *(const float4*)&s_h0[k][12];
            acc[0] += f0.x*w; acc[1] += f0.y*w; acc[2] += f0.z*w; acc[3] += f0.w*w;
            acc[4] += f1.x*w; acc[5] += f1.y*w; acc[6] += f1.z*w; acc[7] += f1.w*w;
            acc[8] += f2.x*w; acc[9] += f2.y*w; acc[10]+= f2.z*w; acc[11]+= f2.w*w;
            acc[12]+= f3.x*w; acc[13]+= f3.y*w; acc[14]+= f3.z*w; acc[15]+= f3.w*w;
        }
        #pragma unroll
        for (int i = 0; i < 16; ++i) s_h1[tx][i] = fmaxf(acc[i], 0.f);
    }
    __syncthreads();
    {
        float bv = b2[tx];
        #pragma unroll
        for (int i = 0; i < 16; ++i) acc[i] = bv;
        for (int k = 0; k < HID; ++k) {
            float w = W2[k * HID + tx];
            float4 f0 = *(const float4*)&s_h1[k][0];
            float4 f1 = *(const float4*)&s_h1[k][4];
            float4 f2 = *(const float4*)&s_h1[k][8];
            float4 f3 = *(const float4*)&s_h1[k][12];
            acc[0] += f0.x*w; acc[1] += f0.y*w; acc[2] += f0.z*w; acc[3] += f0.w*w;
            acc[4] += f1.x*w; acc[5] += f1.y*w; acc[6] += f1.z*w; acc[7] += f1.w*w;
            acc[8] += f2.x*w; acc[9] += f2.y*w; acc[10]+= f2.z*w; acc[11]+= f2.w*w;
            acc[12]+= f3.x*w; acc[13]+= f3.y*w; acc[14]+= f3.z*w; acc[15]+= f3.w*w;
        }
        #pragma unroll
        for (int i = 0; i < 16; ++i) h[(n0 + i) * HID + tx] = acc[i];
    }
}

__global__ __launch_bounds__(256) void edge_gemm_fb_kernel(
    const float* __restrict__ h, const float* __restrict__ x,
    const int* __restrict__ edges, const int* __restrict__ etype,
    const float* __restrict__ edge_table,
    const float* __restrict__ We_l, const float* __restrict__ be_l,
    const float* __restrict__ Wx_l, const float* __restrict__ bx_l,
    float* __restrict__ agg_m, float* __restrict__ agg_x)
{
    __shared__ int s_src[TILE_E], s_dst[TILE_E];
    __shared__ float s_diff[TILE_E][3];
    __shared__ float s_tail[TILE_E][36];
    __shared__ float s_Af[TILE_E][36];
    __shared__ float s_Bf[33][HID];
    __shared__ float s_wx[HID];

    int e0 = blockIdx.x * TILE_E;
    int tx = threadIdx.x;
    int tf = tx & 15;
    int te = tx >> 4;

    if (tx < TILE_E) {
        int s = edges[e0 + tx];
        int d = edges[NE + e0 + tx];
        s_src[tx] = s; s_dst[tx] = d;
        float dx = x[s * 3 + 0] - x[d * 3 + 0];
        float dy = x[s * 3 + 1] - x[d * 3 + 1];
        float dz = x[s * 3 + 2] - x[d * 3 + 2];
        s_diff[tx][0] = dx; s_diff[tx][1] = dy; s_diff[tx][2] = dz;
        s_tail[tx][0] = dx * dx + dy * dy + dz * dz;
        int et = etype[e0 + tx];
        #pragma unroll
        for (int j = 0; j < 32; ++j) s_tail[tx][1 + j] = edge_table[et * 32 + j];
    }
    if (tx < HID) s_wx[tx] = Wx_l[tx];
    __syncthreads();

    float acc[4][8];
    #pragma unroll
    for (int i = 0; i < 4; ++i)
        #pragma unroll
        for (int j = 0; j < 8; ++j) acc[i][j] = 0.f;

    for (int t = 0; t < 9; ++t) {
        int k0 = t * 32;
        int klen = (t == 8) ? 33 : 32;
        __syncthreads();
        if (t < 8) {
            const bool use_src = (t < 4);
            int kbase = (t & 3) * 32;
            for (int q4 = tx; q4 < TILE_E * 8; q4 += 256) {
                int e = q4 >> 3, q = q4 & 7;
                int row = use_src ? s_src[e] : s_dst[e];
                float4 v = *(const float4*)&h[row * HID + kbase + q * 4];
                *(float4*)&s_Af[e][q * 4] = v;
            }
        }
        for (int q4 = tx; q4 < klen * 32; q4 += 256) {
            int kk = q4 >> 5, c4 = q4 & 31;
            float4 v = *(const float4*)&We_l[(k0 + kk) * HID + c4 * 4];
            *(float4*)&s_Bf[kk][c4 * 4] = v;
        }
        __syncthreads();
        const float (*Asrc)[36] = (t == 8) ? (const float (*)[36])s_tail
                                           : (const float (*)[36])s_Af;
        for (int kk = 0; kk < klen; ++kk) {
            float a0 = Asrc[te * 4 + 0][kk];
            float a1 = Asrc[te * 4 + 1][kk];
            float a2 = Asrc[te * 4 + 2][kk];
            float a3 = Asrc[te * 4 + 3][kk];
            float4 bv0 = *(const float4*)&s_Bf[kk][tf * 8];
            float4 bv1 = *(const float4*)&s_Bf[kk][tf * 8 + 4];
            float b[8] = {bv0.x, bv0.y, bv0.z, bv0.w, bv1.x, bv1.y, bv1.z, bv1.w};
            #pragma unroll
            for (int j = 0; j < 8; ++j) {
                acc[0][j] += a0 * b[j];
                acc[1][j] += a1 * b[j];
                acc[2][j] += a2 * b[j];
                acc[3][j] += a3 * b[j];
            }
        }
    }

    float wsum[4];
    #pragma unroll
    for (int i = 0; i < 4; ++i) {
        float p = 0.f;
        #pragma unroll
        for (int j = 0; j < 8; ++j) {
            int f = tf * 8 + j;
            float v = acc[i][j] + be_l[f];
            float m = silu(v);
            acc[i][j] = m;
            p += m * s_wx[f];
        }
        wsum[i] = p;
    }
    #pragma unroll
    for (int off = 1; off < 16; off <<= 1) {
        #pragma unroll
        for (int i = 0; i < 4; ++i) wsum[i] += __shfl_xor(wsum[i], off);
    }
    float bxv = bx_l[0];
    if (tf < 3) {
        #pragma unroll
        for (int i = 0; i < 4; ++i) {
            int e = te * 4 + i;
            float w2 = wsum[i] + bxv;
            atomicAdd(&agg_x[s_dst[e] * 3 + tf], s_diff[e][tf] * w2);
        }
    }
    #pragma unroll
    for (int i = 0; i < 4; ++i) {
        int d = s_dst[te * 4 + i];
        #pragma unroll
        for (int j = 0; j < 8; ++j)
            atomicAdd(&agg_m[d * HID + tf * 8 + j], acc[i][j]);
    }
}

__global__ __launch_bounds__(128) void node_update_fb_kernel(
    float* __restrict__ h, float* __restrict__ x,
    const float* __restrict__ agg_m, const float* __restrict__ agg_x,
    const float* __restrict__ cnt,
    const float* __restrict__ Wh_l, const float* __restrict__ bh_l)
{
    __shared__ float s_in[256][20];
    int n0 = blockIdx.x * 16;
    int tx = threadIdx.x;
    for (int idx = tx; idx < 16 * HID; idx += 128) {
        int i = idx >> 7, k = idx & 127;
        s_in[k][i] = h[(n0 + i) * HID + k];
    }
    for (int idx = tx; idx < 16 * HID; idx += 128) {
        int i = idx >> 7, k = idx & 127;
        s_in[HID + k][i] = agg_m[(n0 + i) * HID + k];
    }
    __syncthreads();
    float acc[16];
    float bv = bh_l[tx];
    #pragma unroll
    for (int i = 0; i < 16; ++i) acc[i] = bv;
    for (int k = 0; k < 256; ++k) {
        float w = Wh_l[k * HID + tx];
        float4 f0 = *(const float4*)&s_in[k][0];
        float4 f1 = *(const float4*)&s_in[k][4];
        float4 f2 = *(const float4*)&s_in[k][8];
        float4 f3 = *(const float4*)&s_in[k][12];
        acc[0] += f0.x*w; acc[1] += f0.y*w; acc[2] += f0.z*w; acc[3] += f0.w*w;
        acc[4] += f1.x*w; acc[5] += f1.y*w; acc[6] += f1.z*w; acc[7] += f1.w*w;
        acc[8] += f2.x*w; acc[9] += f2.y*w; acc[10]+= f2.z*w; acc[11]+= f2.w*w;
        acc[12]+= f3.x*w; acc[13]+= f3.y*w; acc[14]+= f3.z*w; acc[15]+= f3.w*w;
    }
    #pragma unroll
    for (int i = 0; i < 16; ++i) {
        float v = acc[i];
        h[(n0 + i) * HID + tx] = s_in[tx][i] + silu(v);
    }
    if (tx < 48) {
        int i = tx / 3, c = tx % 3;
        int n = n0 + i;
        x[n * 3 + c] += agg_x[n * 3 + c] / (cnt[n] + 1.f);
    }
}

__global__ __launch_bounds__(64) void final_fb_kernel(
    const float* __restrict__ h, const float* __restrict__ x,
    const int* __restrict__ gmask,
    const float* __restrict__ W, const float* __restrict__ b,
    float* __restrict__ out)
{
    __shared__ float s_h[8][HID];
    int n0 = blockIdx.x * 8;
    int tx = threadIdx.x;
    for (int idx = tx; idx < 8 * HID; idx += 64) {
        int i = idx >> 7, k = idx & 127;
        s_h[i][k] = h[(n0 + i) * HID + k];
    }
    __syncthreads();
    float acc[8];
    float bv = b[tx];
    #pragma unroll
    for (int i = 0; i < 8; ++i) acc[i] = bv;
    for (int k = 0; k < HID; ++k) {
        float w = W[k * IN_DIM + tx];
        #pragma unroll
        for (int i = 0; i < 8; ++i) acc[i] += s_h[i][k] * w;
    }
    #pragma unroll
    for (int i = 0; i < 8; ++i) {
        int n = n0 + i;
        out[n * IN_DIM + tx] = gmask[n] ? acc[i] : 0.f;
    }
    if (tx < 24) {
        int i = tx / 3, c = tx % 3;
        int n = n0 + i;
        out[NN * IN_DIM + n * 3 + c] = gmask[n] ? x[n * 3 + c] : 0.f;
    }
}

extern "C" void kernel_launch(void* const* d_in, const int* in_sizes, int n_in,
                              void* d_out, int out_size, void* d_ws, size_t ws_size,
                              hipStream_t stream) {
    const float* H_t   = (const float*)d_in[0];
    const float* X_t   = (const float*)d_in[1];
    const float* cond  = (const float*)d_in[2];
    const float* t_in  = (const float*)d_in[3];
    const int*   edges = (const int*)d_in[4];
    const int*   etype = (const int*)d_in[5];
    const int*   gmask = (const int*)d_in[6];
    const float* W0 = (const float*)d_in[8];
    const float* b0 = (const float*)d_in[9];
    const float* W1 = (const float*)d_in[10];
    const float* b1 = (const float*)d_in[11];
    const float* W2 = (const float*)d_in[12];
    const float* b2 = (const float*)d_in[13];
    const float* edge_table = (const float*)d_in[14];
    const float* We = (const float*)d_in[15];
    const float* be = (const float*)d_in[16];
    const float* Wx = (const float*)d_in[17];
    const float* bx = (const float*)d_in[18];
    const float* Wh = (const float*)d_in[19];
    const float* bh = (const float*)d_in[20];
    const float* h2i_W = (const float*)d_in[21];
    const float* h2i_b = (const float*)d_in[22];

    char* p = (char*)d_ws;
    float* h = (float*)p;           p += (size_t)NN * HID * 4;
    u16* h_bf = (u16*)p;            p += (size_t)NN * HID * 2;
    float* xa = (float*)p;          p += (size_t)NN * 3 * 4;
    float* xb = (float*)p;          p += (size_t)NN * 3 * 4;
    u16* Cbf = (u16*)p;             p += (size_t)NN * 256 * 2;
    u16* Bpack = (u16*)p;           p += (size_t)PACK_TOT * 2;
    float* tv = (float*)p;          p += (size_t)768 * 4;
    float* wed2 = (float*)p;        p += (size_t)384 * 4;
    int* row_start = (int*)p;       p += (size_t)(NN + 4) * 4;
    int* deg = (int*)p;             p += (size_t)NN * 4;
    int* head = (int*)p;            p += (size_t)NN * 4;
    int* src_s = (int*)p;           p += (size_t)NE * 4;
    int* dst_s = (int*)p;           p += (size_t)NE * 4;
    size_t need = (size_t)(p - (char*)d_ws);

    if (ws_size >= need) {
        hipMemsetAsync(deg, 0, NN * sizeof(int), stream);
        hist_kernel<<<256, 256, 0, stream>>>(X_t, edges, xa, deg);
        scan_kernel<<<1, 256, 0, stream>>>(deg, row_start, head);
        scatter_kernel<<<256, 256, 0, stream>>>(edges, etype, head, src_s, dst_s);
        pack_all_kernel<<<(PACK_TOT + 255) / 256, 256, 0, stream>>>(
            We, W0, W1, W2, Wh, h2i_W, Bpack);
        precomp_tv_kernel<<<5, 256, 0, stream>>>(edge_table, We, be, tv, wed2);
        node_mlp_mfma_kernel<<<NB64, 256, 0, stream>>>(
            H_t, cond, t_in,
            Bpack + OFF_W0, b0, Bpack + OFF_W1, b1, Bpack + OFF_W2, b2,
            h, h_bf);
        for (int l = 0; l < 3; ++l) {
            cvec_kernel<<<NB64, 256, 0, stream>>>(
                h_bf, Bpack + OFF_WE + (size_t)l * 40960, Cbf);
            const float* xin = (l & 1) ? xb : xa;
            float* xout = (l & 1) ? xa : xb;
            node_fused_kernel<<<NN / NUB, 512, 0, stream>>>(
                h, h_bf, xin, xout, Cbf, src_s, dst_s, row_start,
                tv + (size_t)l * 256, wed2 + (size_t)l * 128,
                Wx + l * HID, bx + l,
                Bpack + OFF_WH + (size_t)l * 32768, bh + l * HID);
        }
        // layers: l0 xa->xb, l1 xb->xa, l2 xa->xb  => final x lives in xb
        final_mfma_kernel<<<NB64, 256, 0, stream>>>(
            h_bf, xb, gmask, Bpack + OFF_H2I, h2i_b, (float*)d_out);
    } else {
        // fallback: scalar atomic path (~21 MB)
        float* ws    = (float*)d_ws;
        float* fh    = ws;
        float* fx    = fh + NN * HID;
        float* cnt   = fx + NN * 3;
        float* fagg_m = cnt + NN;
        float* fagg_x = fagg_m + NN * HID;

        hipMemsetAsync(cnt, 0, NN * sizeof(float), stream);
        init_fb_kernel<<<256, 256, 0, stream>>>(X_t, edges, fx, cnt);
        node_mlp_kernel<<<NN / 16, 128, 0, stream>>>(H_t, cond, t_in,
                                                     W0, b0, W1, b1, W2, b2, fh);
        for (int l = 0; l < 3; ++l) {
            hipMemsetAsync(fagg_m, 0, (size_t)NN * 131 * sizeof(float), stream);
            edge_gemm_fb_kernel<<<NE / TILE_E, 256, 0, stream>>>(
                fh, fx, edges, etype, edge_table,
                We + (size_t)l * DE * HID, be + l * HID,
                Wx + l * HID, bx + l, fagg_m, fagg_x);
            node_update_fb_kernel<<<NN / 16, 128, 0, stream>>>(
                fh, fx, fagg_m, fagg_x, cnt,
                Wh + (size_t)l * 256 * HID, bh + l * HID);
        }
        final_fb_kernel<<<NN / 8, 64, 0, stream>>>(fh, fx, gmask, h2i_W, h2i_b, (float*)d_out);
    }
}

// Round 2
// 372.046 us; speedup vs baseline: 1.0824x; 1.0663x over previous
//
#include <hip/hip_runtime.h>
#include <math.h>

#define NN 20000
#define NE 256000
#define IN_DIM 64
#define HID 128
#define DE 289     // 2*HID + 1 + 32
#define D0 320     // IN_DIM + 2*HID
#define TILE_E 64
#define NB64 313   // ceil(NN/64)
#define NUB 8      // nodes per block (fused node kernel)
#define SRCMASK 0x3FFFFFFF

typedef unsigned short u16;
typedef unsigned int u32;
typedef unsigned long long u64;
typedef __attribute__((ext_vector_type(8))) short short8;
typedef __attribute__((ext_vector_type(4))) float float4v;

// Bpack layout offsets (u16 elements)
#define OFF_WE   0          // 3 x 40960 (K=289 pad 320, N=128) — tiles 0..3 = We rows 0..255
#define OFF_W0   122880     // 40960 (K=320, N=128)
#define OFF_W1   163840     // 16384 (K=128, N=128)
#define OFF_W2   180224     // 16384
#define OFF_WH   196608     // 3 x 32768 (K=256, N=128)
#define OFF_H2I  294912     // 8192 (K=128, N=64)
#define PACK_TOT 303104

static __device__ __forceinline__ u16 f2bf(float f) {
    unsigned int u = __float_as_uint(f);
    u += 0x7fffu + ((u >> 16) & 1u);
    return (u16)(u >> 16);
}
static __device__ __forceinline__ float bf2f(u16 s) {
    return __uint_as_float(((unsigned int)s) << 16);
}
static __device__ __forceinline__ float bflo(u32 u) { return bf2f((u16)(u & 0xffffu)); }
static __device__ __forceinline__ float bfhi(u32 u) { return bf2f((u16)(u >> 16)); }
static __device__ __forceinline__ u32 pack2(float a, float b) {
    return (u32)f2bf(a) | ((u32)f2bf(b) << 16);
}
static __device__ __forceinline__ uint4 pack8(const float* v) {
    uint4 r;
    r.x = (u32)f2bf(v[0]) | ((u32)f2bf(v[1]) << 16);
    r.y = (u32)f2bf(v[2]) | ((u32)f2bf(v[3]) << 16);
    r.z = (u32)f2bf(v[4]) | ((u32)f2bf(v[5]) << 16);
    r.w = (u32)f2bf(v[6]) | ((u32)f2bf(v[7]) << 16);
    return r;
}
static __device__ __forceinline__ float silu(float v) {
    return v * (1.f / (1.f + __expf(-v)));
}

// ================= CSR build =================
__global__ __launch_bounds__(256) void hist_kernel(
    const float* __restrict__ X_t, const int* __restrict__ edges,
    float* __restrict__ x, int* __restrict__ deg)
{
    int gid = blockIdx.x * blockDim.x + threadIdx.x;
    int stride = gridDim.x * blockDim.x;
    for (int i = gid; i < NN * 3; i += stride) x[i] = X_t[i];
    for (int e = gid; e < NE; e += stride)
        atomicAdd(&deg[edges[NE + e]], 1);
}

__global__ __launch_bounds__(1024) void scan_kernel(
    const int* __restrict__ deg, int* __restrict__ row_start, int* __restrict__ head)
{
    __shared__ int s[1024];
    int tx = threadIdx.x;
    const int per = (NN + 1023) / 1024;
    int st = tx * per, en = st + per;
    if (st > NN) st = NN;
    if (en > NN) en = NN;
    int sum = 0;
    for (int i = st; i < en; ++i) sum += deg[i];
    s[tx] = sum;
    __syncthreads();
    for (int off = 1; off < 1024; off <<= 1) {
        int t = (tx >= off) ? s[tx - off] : 0;
        __syncthreads();
        s[tx] += t;
        __syncthreads();
    }
    int run = (tx == 0) ? 0 : s[tx - 1];
    for (int i = st; i < en; ++i) {
        row_start[i] = run; head[i] = run; run += deg[i];
    }
    if (tx == 1023) row_start[NN] = run;
}

// permute edges into dst-sorted order; pack etype into src bit 30
__global__ __launch_bounds__(256) void scatter_kernel(
    const int* __restrict__ edges, const int* __restrict__ etype,
    int* __restrict__ head,
    int* __restrict__ src_s)
{
    int gid = blockIdx.x * blockDim.x + threadIdx.x;
    int stride = gridDim.x * blockDim.x;
    for (int e = gid; e < NE; e += stride) {
        int d = edges[NE + e];
        int p = atomicAdd(&head[d], 1);
        src_s[p] = edges[e] | (etype[e] << 30);
    }
}

// ================= weight frag-order packing =================
__global__ __launch_bounds__(256) void pack_all_kernel(
    const float* __restrict__ We, const float* __restrict__ W0,
    const float* __restrict__ W1, const float* __restrict__ W2,
    const float* __restrict__ Wh, const float* __restrict__ h2i,
    u16* __restrict__ Bp)
{
    int idx = blockIdx.x * 256 + threadIdx.x;
    if (idx >= PACK_TOT) return;
    const float* src; int N = 128, Ksrc; int r;
    if (idx < OFF_W0) {
        int layer = idx / 40960; r = idx - layer * 40960;
        src = We + (size_t)layer * DE * HID; Ksrc = DE;
    } else if (idx < OFF_W1) { r = idx - OFF_W0; src = W0; Ksrc = 320; }
    else if (idx < OFF_W2)   { r = idx - OFF_W1; src = W1; Ksrc = 128; }
    else if (idx < OFF_WH)   { r = idx - OFF_W2; src = W2; Ksrc = 128; }
    else if (idx < OFF_H2I) {
        int t = idx - OFF_WH; int layer = t / 32768; r = t - layer * 32768;
        src = Wh + (size_t)layer * 256 * HID; Ksrc = 256;
    } else { r = idx - OFF_H2I; src = h2i; Ksrc = 128; N = 64; }
    int ntc = N / 16;
    int j = r & 7, lane = (r >> 3) & 63;
    int rem = r >> 9;
    int nt = rem % ntc, ks = rem / ntc;
    int k = ks * 32 + ((lane >> 4) << 3) + j;
    int c = nt * 16 + (lane & 15);
    Bp[idx] = f2bf((k < Ksrc) ? src[(size_t)k * N + c] : 0.f);
}

// ================= edge tail precompute (f32) =================
__global__ __launch_bounds__(256) void precomp_tv_kernel(
    const float* __restrict__ edge_table, const float* __restrict__ We,
    const float* __restrict__ be, float* __restrict__ tv, float* __restrict__ wed2)
{
    int idx = blockIdx.x * 256 + threadIdx.x;
    if (idx < 768) {
        int f = idx & 127, t = (idx >> 7) & 1, l = idx >> 8;
        float acc = be[l * 128 + f];
        const float* W = We + (size_t)l * DE * HID;
        #pragma unroll
        for (int k = 0; k < 32; ++k)
            acc += edge_table[t * 32 + k] * W[(size_t)(257 + k) * HID + f];
        tv[l * 256 + t * 128 + f] = acc;
    } else if (idx < 1152) {
        int r = idx - 768;
        int f = r & 127, l = r >> 7;
        wed2[l * 128 + f] = We[(size_t)l * DE * HID + (size_t)256 * HID + f];
    }
}

// ================= node MLP: MFMA, 64 nodes/block + fused cvec layer-0 =================
__global__ __launch_bounds__(256) void node_mlp_mfma_kernel(
    const float* __restrict__ H_t, const float* __restrict__ cond,
    const float* __restrict__ t_in,
    const u16* __restrict__ W0p, const float* __restrict__ b0,
    const u16* __restrict__ W1p, const float* __restrict__ b1,
    const u16* __restrict__ W2p, const float* __restrict__ b2,
    const u16* __restrict__ WEp, u16* __restrict__ Cbf,
    float* __restrict__ h, u16* __restrict__ h_bf)
{
    __shared__ u16 s_A[64 * 64];
    __shared__ u16 s_B[64 * 128];
    __shared__ u16 s_h[64 * 128];
    __shared__ float s_t[64];

    int tx = threadIdx.x;
    int n0 = blockIdx.x * 64;
    int l = tx & 63, w = tx >> 6;
    int mt_base = (w & 1) * 2, nt_base = (w >> 1) * 4;
    const float cfr = -logf(10000.f) / 63.f;

    if (tx < 64) s_t[tx] = (n0 + tx < NN) ? t_in[n0 + tx] : 0.f;

    float4v acc[2][4];
    #pragma unroll
    for (int mi = 0; mi < 2; ++mi)
        #pragma unroll
        for (int ni = 0; ni < 4; ++ni) acc[mi][ni] = (float4v){0.f,0.f,0.f,0.f};

    for (int t = 0; t < 5; ++t) {
        __syncthreads();
        #pragma unroll
        for (int it = 0; it < 2; ++it) {
            int flat = it * 256 + tx;
            int n = flat >> 3, sl = flat & 7;
            int c = sl ^ (n & 7);
            int k0 = t * 64 + c * 8;
            float tv8[8];
            int gn = n0 + n;
            if (gn < NN) {
                if (k0 < 192) {
                    const float* src = (k0 < 64) ? &H_t[(size_t)gn * IN_DIM + k0]
                                                 : &cond[(size_t)gn * HID + (k0 - 64)];
                    float4 a = *(const float4*)src;
                    float4 b = *(const float4*)(src + 4);
                    tv8[0]=a.x; tv8[1]=a.y; tv8[2]=a.z; tv8[3]=a.w;
                    tv8[4]=b.x; tv8[5]=b.y; tv8[6]=b.z; tv8[7]=b.w;
                } else {
                    float tv = s_t[n];
                    int jj = (k0 - 192) & 63;
                    bool is_sin = (k0 < 256);
                    #pragma unroll
                    for (int jx = 0; jx < 8; ++jx) {
                        float ang = tv * __expf(cfr * (float)(jj + jx));
                        tv8[jx] = is_sin ? __sinf(ang) : __cosf(ang);
                    }
                }
            } else {
                #pragma unroll
                for (int jx = 0; jx < 8; ++jx) tv8[jx] = 0.f;
            }
            *(uint4*)&s_A[n * 64 + sl * 8] = pack8(tv8);
        }
        #pragma unroll
        for (int it = 0; it < 4; ++it) {
            int flat = it * 256 + tx;
            ((uint4*)s_B)[flat] = ((const uint4*)(W0p + (size_t)t * 8192))[flat];
        }
        __syncthreads();
        #pragma unroll
        for (int s = 0; s < 2; ++s) {
            short8 af[2], bfv[4];
            #pragma unroll
            for (int mi = 0; mi < 2; ++mi) {
                int m = (mt_base + mi) * 16 + (l & 15);
                int c = s * 4 + (l >> 4);
                int slot = c ^ (l & 7);
                af[mi] = *(const short8*)(s_A + m * 64 + slot * 8);
            }
            #pragma unroll
            for (int ni = 0; ni < 4; ++ni)
                bfv[ni] = *(const short8*)(s_B + ((s * 8 + nt_base + ni) * 64 + l) * 8);
            #pragma unroll
            for (int mi = 0; mi < 2; ++mi)
                #pragma unroll
                for (int ni = 0; ni < 4; ++ni)
                    acc[mi][ni] = __builtin_amdgcn_mfma_f32_16x16x32_bf16(
                        af[mi], bfv[ni], acc[mi][ni], 0, 0, 0);
        }
    }
    #pragma unroll
    for (int mi = 0; mi < 2; ++mi) {
        #pragma unroll
        for (int ni = 0; ni < 4; ++ni) {
            int f = (nt_base + ni) * 16 + (l & 15);
            float bv = b0[f];
            #pragma unroll
            for (int r = 0; r < 4; ++r) {
                int m = (mt_base + mi) * 16 + (l >> 4) * 4 + r;
                float v = fmaxf(acc[mi][ni][r] + bv, 0.f);
                int slot = (f >> 3) ^ (m & 7);
                s_h[m * 128 + slot * 8 + (f & 7)] = f2bf(v);
            }
            acc[mi][ni] = (float4v){0.f,0.f,0.f,0.f};
        }
    }
    for (int t = 0; t < 2; ++t) {
        __syncthreads();
        #pragma unroll
        for (int it = 0; it < 4; ++it) {
            int flat = it * 256 + tx;
            ((uint4*)s_B)[flat] = ((const uint4*)(W1p + (size_t)t * 8192))[flat];
        }
        __syncthreads();
        #pragma unroll
        for (int s = 0; s < 2; ++s) {
            short8 af[2], bfv[4];
            #pragma unroll
            for (int mi = 0; mi < 2; ++mi) {
                int m = (mt_base + mi) * 16 + (l & 15);
                int c = t * 8 + s * 4 + (l >> 4);
                int slot = c ^ (l & 7);
                af[mi] = *(const short8*)(s_h + m * 128 + slot * 8);
            }
            #pragma unroll
            for (int ni = 0; ni < 4; ++ni)
                bfv[ni] = *(const short8*)(s_B + ((s * 8 + nt_base + ni) * 64 + l) * 8);
            #pragma unroll
            for (int mi = 0; mi < 2; ++mi)
                #pragma unroll
                for (int ni = 0; ni < 4; ++ni)
                    acc[mi][ni] = __builtin_amdgcn_mfma_f32_16x16x32_bf16(
                        af[mi], bfv[ni], acc[mi][ni], 0, 0, 0);
        }
    }
    __syncthreads();
    #pragma unroll
    for (int mi = 0; mi < 2; ++mi) {
        #pragma unroll
        for (int ni = 0; ni < 4; ++ni) {
            int f = (nt_base + ni) * 16 + (l & 15);
            float bv = b1[f];
            #pragma unroll
            for (int r = 0; r < 4; ++r) {
                int m = (mt_base + mi) * 16 + (l >> 4) * 4 + r;
                float v = fmaxf(acc[mi][ni][r] + bv, 0.f);
                int slot = (f >> 3) ^ (m & 7);
                s_h[m * 128 + slot * 8 + (f & 7)] = f2bf(v);
            }
            acc[mi][ni] = (float4v){0.f,0.f,0.f,0.f};
        }
    }
    for (int t = 0; t < 2; ++t) {
        __syncthreads();
        #pragma unroll
        for (int it = 0; it < 4; ++it) {
            int flat = it * 256 + tx;
            ((uint4*)s_B)[flat] = ((const uint4*)(W2p + (size_t)t * 8192))[flat];
        }
        __syncthreads();
        #pragma unroll
        for (int s = 0; s < 2; ++s) {
            short8 af[2], bfv[4];
            #pragma unroll
            for (int mi = 0; mi < 2; ++mi) {
                int m = (mt_base + mi) * 16 + (l & 15);
                int c = t * 8 + s * 4 + (l >> 4);
                int slot = c ^ (l & 7);
                af[mi] = *(const short8*)(s_h + m * 128 + slot * 8);
            }
            #pragma unroll
            for (int ni = 0; ni < 4; ++ni)
                bfv[ni] = *(const short8*)(s_B + ((s * 8 + nt_base + ni) * 64 + l) * 8);
            #pragma unroll
            for (int mi = 0; mi < 2; ++mi)
                #pragma unroll
                for (int ni = 0; ni < 4; ++ni)
                    acc[mi][ni] = __builtin_amdgcn_mfma_f32_16x16x32_bf16(
                        af[mi], bfv[ni], acc[mi][ni], 0, 0, 0);
        }
    }
    // final h: write globals AND store into s_h (swizzled) for the fused cvec
    __syncthreads();   // protect s_h against pending W2-stage reads
    #pragma unroll
    for (int mi = 0; mi < 2; ++mi) {
        #pragma unroll
        for (int ni = 0; ni < 4; ++ni) {
            int f = (nt_base + ni) * 16 + (l & 15);
            float bv = b2[f];
            #pragma unroll
            for (int r = 0; r < 4; ++r) {
                int m = (mt_base + mi) * 16 + (l >> 4) * 4 + r;
                int gn = n0 + m;
                float v = acc[mi][ni][r] + bv;
                int slot = (f >> 3) ^ (m & 7);
                s_h[m * 128 + slot * 8 + (f & 7)] = f2bf(v);
                if (gn < NN) {
                    h[(size_t)gn * HID + f] = v;
                    h_bf[(size_t)gn * HID + f] = f2bf(v);
                }
            }
        }
    }

    // ---- fused cvec (layer 0): Cbf[n][0:128]=h@We_src, [128:256]=h@We_dst ----
    for (int sd = 0; sd < 2; ++sd) {
        #pragma unroll
        for (int mi = 0; mi < 2; ++mi)
            #pragma unroll
            for (int ni = 0; ni < 4; ++ni) acc[mi][ni] = (float4v){0.f,0.f,0.f,0.f};
        #pragma unroll
        for (int th = 0; th < 2; ++th) {
            int t = sd * 2 + th;
            __syncthreads();
            #pragma unroll
            for (int it = 0; it < 4; ++it) {
                int flat = it * 256 + tx;
                ((uint4*)s_B)[flat] = ((const uint4*)(WEp + (size_t)t * 8192))[flat];
            }
            __syncthreads();
            #pragma unroll
            for (int s = 0; s < 2; ++s) {
                short8 af[2], bfv[4];
                #pragma unroll
                for (int mi = 0; mi < 2; ++mi) {
                    int m = (mt_base + mi) * 16 + (l & 15);
                    int c = th * 8 + s * 4 + (l >> 4);
                    int slot = c ^ (l & 7);
                    af[mi] = *(const short8*)(s_h + m * 128 + slot * 8);
                }
                #pragma unroll
                for (int ni = 0; ni < 4; ++ni)
                    bfv[ni] = *(const short8*)(s_B + ((s * 8 + nt_base + ni) * 64 + l) * 8);
                #pragma unroll
                for (int mi = 0; mi < 2; ++mi)
                    #pragma unroll
                    for (int ni = 0; ni < 4; ++ni)
                        acc[mi][ni] = __builtin_amdgcn_mfma_f32_16x16x32_bf16(
                            af[mi], bfv[ni], acc[mi][ni], 0, 0, 0);
            }
        }
        #pragma unroll
        for (int mi = 0; mi < 2; ++mi) {
            #pragma unroll
            for (int ni = 0; ni < 4; ++ni) {
                int f = sd * 128 + (nt_base + ni) * 16 + (l & 15);
                #pragma unroll
                for (int r = 0; r < 4; ++r) {
                    int m = (mt_base + mi) * 16 + (l >> 4) * 4 + r;
                    int gn = n0 + m;
                    if (gn < NN)
                        Cbf[(size_t)gn * 256 + f] = f2bf(acc[mi][ni][r]);
                }
            }
        }
    }
}

// ================= cvec (layers 1,2): C[n][0:128]=h@We_src, C[n][128:256]=h@We_dst =================
__global__ __launch_bounds__(256) void cvec_kernel(
    const u16* __restrict__ h_bf, const u16* __restrict__ WEp,
    u16* __restrict__ Cbf)
{
    __shared__ u16 s_A[64 * 64];
    __shared__ u16 s_B[64 * 128];

    int tx = threadIdx.x;
    int n0 = blockIdx.x * 64;
    int l = tx & 63, w = tx >> 6;
    int mt_base = (w & 1) * 2, nt_base = (w >> 1) * 4;

    float4v acc[2][2][4];  // [side][mi][ni]
    #pragma unroll
    for (int sd = 0; sd < 2; ++sd)
        #pragma unroll
        for (int mi = 0; mi < 2; ++mi)
            #pragma unroll
            for (int ni = 0; ni < 4; ++ni)
                acc[sd][mi][ni] = (float4v){0.f,0.f,0.f,0.f};

    for (int t = 0; t < 4; ++t) {
        __syncthreads();
        #pragma unroll
        for (int it = 0; it < 2; ++it) {
            int flat = it * 256 + tx;
            int n = flat >> 3, sl = flat & 7;
            int c = sl ^ (n & 7);
            int gn = n0 + n;
            uint4 v = make_uint4(0,0,0,0);
            if (gn < NN) v = *(const uint4*)(h_bf + (size_t)gn * 128 + (t & 1) * 64 + c * 8);
            *(uint4*)&s_A[n * 64 + sl * 8] = v;
        }
        #pragma unroll
        for (int it = 0; it < 4; ++it) {
            int flat = it * 256 + tx;
            ((uint4*)s_B)[flat] = ((const uint4*)(WEp + (size_t)t * 8192))[flat];
        }
        __syncthreads();
        int sd = t >> 1;
        #pragma unroll
        for (int s = 0; s < 2; ++s) {
            short8 af[2], bfv[4];
            #pragma unroll
            for (int mi = 0; mi < 2; ++mi) {
                int m = (mt_base + mi) * 16 + (l & 15);
                int c = s * 4 + (l >> 4);
                int slot = c ^ (l & 7);
                af[mi] = *(const short8*)(s_A + m * 64 + slot * 8);
            }
            #pragma unroll
            for (int ni = 0; ni < 4; ++ni)
                bfv[ni] = *(const short8*)(s_B + ((s * 8 + nt_base + ni) * 64 + l) * 8);
            #pragma unroll
            for (int mi = 0; mi < 2; ++mi)
                #pragma unroll
                for (int ni = 0; ni < 4; ++ni)
                    acc[sd][mi][ni] = __builtin_amdgcn_mfma_f32_16x16x32_bf16(
                        af[mi], bfv[ni], acc[sd][mi][ni], 0, 0, 0);
        }
    }
    #pragma unroll
    for (int sd = 0; sd < 2; ++sd) {
        #pragma unroll
        for (int mi = 0; mi < 2; ++mi) {
            #pragma unroll
            for (int ni = 0; ni < 4; ++ni) {
                int f = sd * 128 + (nt_base + ni) * 16 + (l & 15);
                #pragma unroll
                for (int r = 0; r < 4; ++r) {
                    int m = (mt_base + mi) * 16 + (l >> 4) * 4 + r;
                    int gn = n0 + m;
                    if (gn < NN)
                        Cbf[(size_t)gn * 256 + f] = f2bf(acc[sd][mi][ni][r]);
                }
            }
        }
    }
}

// ================= fused node update v5 =================
// NUB=8 nodes/block, 512 thr, wave w = node w. Wave-private edge staging:
//  - lane l holds edge l's src|et and geometry in REGISTERS (no LDS, no pre-loop barrier)
//  - consume-time broadcast via __shfl (ds_bpermute)
//  - 4-deep Cbf gather pipeline per parity (8 gathers in flight per wave)
//  - single block barrier (before Wh GEMM); Wh B-fragments straight from L2
__global__ __launch_bounds__(512, 4) void node_fused_kernel(
    float* __restrict__ h, u16* __restrict__ h_bf,
    const float* __restrict__ x_in, float* __restrict__ x_out,
    const u16* __restrict__ Cbf,
    const int* __restrict__ src_s,
    const int* __restrict__ row_start,
    const float* __restrict__ tv_l, const float* __restrict__ wed2_l,
    const float* __restrict__ Wx_l, const float* __restrict__ bx_l,
    const u16* __restrict__ Whp_l, const float* __restrict__ bh_l)
{
    __shared__ u16 s_A[16 * 256];      // 8 KB: rows 0..7 = [h | agg] xor-swizzled, rows 8..15 zero

    int tx = threadIdx.x;
    int n0 = blockIdx.x * NUB;
    int l = tx & 63, w = tx >> 6;      // 8 waves; wave w owns node i = w
    int i = w;
    int gn = n0 + i;
    int p = l & 31, q = l >> 5;        // feat-chunk (4 feats), edge parity

    // ---- stage h rows (0..7) + zero pad rows (chunks 0..15) ----
    if (tx < 256) {
        int n = tx >> 4, c = tx & 15;
        int slot = c ^ (n & 7);
        uint4 v = make_uint4(0, 0, 0, 0);
        if (n < NUB) v = *(const uint4*)(h_bf + (size_t)(n0 + n) * 128 + c * 8);
        *(uint4*)&s_A[n * 256 + slot * 8] = v;
    } else if (tx < 384) {
        int n = 8 + ((tx - 256) >> 4), c = 16 + (tx & 15);
        int slot = c ^ (n & 7);
        *(uint4*)&s_A[n * 256 + slot * 8] = make_uint4(0, 0, 0, 0);
    }

    // ---- per-thread constants (4 feats) ----
    float c0[4], d01[4], wed[4], wx[4];
    {
        uint2 cd = *(const uint2*)(Cbf + (size_t)gn * 256 + 128 + p * 4);
        float cdv0 = bflo(cd.x), cdv1 = bfhi(cd.x), cdv2 = bflo(cd.y), cdv3 = bfhi(cd.y);
        float4 t0 = *(const float4*)(tv_l + p * 4);
        float4 t1 = *(const float4*)(tv_l + 128 + p * 4);
        float4 wd = *(const float4*)(wed2_l + p * 4);
        float4 wv = *(const float4*)(Wx_l + p * 4);
        c0[0] = t0.x + cdv0; c0[1] = t0.y + cdv1; c0[2] = t0.z + cdv2; c0[3] = t0.w + cdv3;
        d01[0] = t1.x - t0.x; d01[1] = t1.y - t0.y; d01[2] = t1.z - t0.z; d01[3] = t1.w - t0.w;
        wed[0] = wd.x; wed[1] = wd.y; wed[2] = wd.z; wed[3] = wd.w;
        wx[0] = wv.x; wx[1] = wv.y; wx[2] = wv.z; wx[3] = wv.w;
    }
    float bx32 = bx_l[0] * (1.f / 32.f);

    int rs = row_start[gn], re = row_start[gn + 1];
    int d = re - rs;

    // own-node coords (wave-uniform)
    float xd0 = x_in[gn * 3 + 0], xd1 = x_in[gn * 3 + 1], xd2 = x_in[gn * 3 + 2];

    float ag[4] = {0.f, 0.f, 0.f, 0.f};
    float sx = 0.f, sy = 0.f, sz = 0.f;

    for (int e0 = 0; e0 < d; e0 += 64) {
        int nchunk = d - e0; if (nchunk > 64) nchunk = 64;
        // stage: lane l holds edge (e0+l)
        int sp_l = (l < nchunk) ? src_s[rs + e0 + l] : 0;
        float gx_l = 0.f, gy_l = 0.f, gz_l = 0.f, d2_l = 0.f;
        if (l < nchunk) {
            int sm = sp_l & SRCMASK;
            gx_l = x_in[sm * 3 + 0] - xd0;
            gy_l = x_in[sm * 3 + 1] - xd1;
            gz_l = x_in[sm * 3 + 2] - xd2;
            d2_l = gx_l * gx_l + gy_l * gy_l + gz_l * gz_l;
        }

        auto FETCH = [&](int lj, uint2& cc, float& et) {
            int spE = __shfl(sp_l, lj);
            cc = make_uint2(0u, 0u); et = 0.f;
            if (lj < nchunk) {
                cc = *(const uint2*)(Cbf + (size_t)(spE & SRCMASK) * 256 + p * 4);
                et = (float)((u32)spE >> 30);
            }
        };
        auto PROC = [&](int lj, uint2 cc, float ee) {
            float dxe = __shfl(gx_l, lj);
            float dye = __shfl(gy_l, lj);
            float dze = __shfl(gz_l, lj);
            float d2e = __shfl(d2_l, lj);
            float av[4];
            av[0] = bflo(cc.x); av[1] = bfhi(cc.x);
            av[2] = bflo(cc.y); av[3] = bfhi(cc.y);
            float wpart = bx32;
            #pragma unroll
            for (int f = 0; f < 4; ++f) {
                float t = __fmaf_rn(d2e, wed[f], c0[f]);
                t = __fmaf_rn(ee, d01[f], t);
                float v = av[f] + t;
                float m = silu(v);
                ag[f] += m;
                wpart = __fmaf_rn(m, wx[f], wpart);
            }
            sx = __fmaf_rn(dxe, wpart, sx);
            sy = __fmaf_rn(dye, wpart, sy);
            sz = __fmaf_rn(dze, wpart, sz);
        };

        // 4-slot pipeline per parity (8 gathers in flight per wave)
        int ljA = q, ljB = q + 2, ljC = q + 4, ljD = q + 6, ljn = q + 8;
        uint2 ccA, ccB, ccC, ccD; float etA, etB, etC, etD;
        FETCH(ljA, ccA, etA); FETCH(ljB, ccB, etB);
        FETCH(ljC, ccC, etC); FETCH(ljD, ccD, etD);
        while (ljA < nchunk) {
            PROC(ljA, ccA, etA); ljA = ljn; ljn += 2; FETCH(ljA, ccA, etA);
            if (ljB >= nchunk) break;
            PROC(ljB, ccB, etB); ljB = ljn; ljn += 2; FETCH(ljB, ccB, etB);
            if (ljC >= nchunk) break;
            PROC(ljC, ccC, etC); ljC = ljn; ljn += 2; FETCH(ljC, ccC, etC);
            if (ljD >= nchunk) break;
            PROC(ljD, ccD, etD); ljD = ljn; ljn += 2; FETCH(ljD, ccD, etD);
        }
    }

    // ---- reductions (within this node's single wave) ----
    #pragma unroll
    for (int f = 0; f < 4; ++f) ag[f] += __shfl_xor(ag[f], 32);   // combine parities
    #pragma unroll
    for (int off = 1; off <= 32; off <<= 1) {
        sx += __shfl_xor(sx, off);
        sy += __shfl_xor(sy, off);
        sz += __shfl_xor(sz, off);
    }
    if (l < 32) {
        int c2 = 16 + (p >> 1);
        int slot = c2 ^ (i & 7);
        uint2 o;
        o.x = pack2(ag[0], ag[1]);
        o.y = pack2(ag[2], ag[3]);
        *(uint2*)&s_A[i * 256 + slot * 8 + (p & 1) * 4] = o;
    }
    if (l == 0) {
        float inv = 1.f / ((float)d + 1.f);
        x_out[gn * 3 + 0] = xd0 + sx * inv;
        x_out[gn * 3 + 1] = xd1 + sy * inv;
        x_out[gn * 3 + 2] = xd2 + sz * inv;
    }

    __syncthreads();

    // ---- Wh GEMM: wave w = N-tile w; B fragments straight from L2 ----
    float4v acc = (float4v){0.f, 0.f, 0.f, 0.f};
    #pragma unroll
    for (int t = 0; t < 4; ++t) {
        #pragma unroll
        for (int s = 0; s < 2; ++s) {
            int m = l & 15;
            int c = t * 8 + s * 4 + (l >> 4);
            int slot = c ^ (l & 7);
            short8 af = *(const short8*)(s_A + m * 256 + slot * 8);
            short8 bfv = *(const short8*)(Whp_l + (size_t)t * 8192 + ((s * 8 + w) * 64 + l) * 8);
            acc = __builtin_amdgcn_mfma_f32_16x16x32_bf16(af, bfv, acc, 0, 0, 0);
        }
    }
    // epilogue: h += silu(acc + bh)  (only rows 0..7 are real nodes)
    {
        int f = w * 16 + (l & 15);
        float bv = bh_l[f];
        #pragma unroll
        for (int r = 0; r < 4; ++r) {
            int m = (l >> 4) * 4 + r;
            if (m < NUB) {
                int gn2 = n0 + m;
                float v = acc[r] + bv;
                float hn = h[(size_t)gn2 * HID + f] + silu(v);
                h[(size_t)gn2 * HID + f] = hn;
                h_bf[(size_t)gn2 * HID + f] = f2bf(hn);
            }
        }
    }
}

// ================= final: MFMA h2i, 64 nodes/block =================
__global__ __launch_bounds__(256) void final_mfma_kernel(
    const u16* __restrict__ h_bf, const float* __restrict__ x,
    const int* __restrict__ gmask,
    const u16* __restrict__ h2ip, const float* __restrict__ b,
    float* __restrict__ out)
{
    __shared__ u16 s_A[64 * 128];
    __shared__ u16 s_B[4096];

    int tx = threadIdx.x;
    int n0 = blockIdx.x * 64;
    int l = tx & 63, w = tx >> 6;
    int mt_base = (w & 1) * 2, nt_base = (w >> 1) * 2;

    #pragma unroll
    for (int it = 0; it < 4; ++it) {
        int flat = it * 256 + tx;
        int n = flat >> 4, c = flat & 15;
        int slot = c ^ (n & 7);
        int gn = n0 + n;
        uint4 v = make_uint4(0,0,0,0);
        if (gn < NN) v = *(const uint4*)(h_bf + (size_t)gn * 128 + c * 8);
        *(uint4*)&s_A[n * 128 + slot * 8] = v;
    }

    float4v acc[2][2];
    #pragma unroll
    for (int mi = 0; mi < 2; ++mi)
        #pragma unroll
        for (int ni = 0; ni < 2; ++ni) acc[mi][ni] = (float4v){0.f,0.f,0.f,0.f};

    for (int t = 0; t < 2; ++t) {
        __syncthreads();
        #pragma unroll
        for (int it = 0; it < 2; ++it) {
            int flat = it * 256 + tx;
            ((uint4*)s_B)[flat] = ((const uint4*)(h2ip + (size_t)t * 4096))[flat];
        }
        __syncthreads();
        #pragma unroll
        for (int s = 0; s < 2; ++s) {
            short8 af[2], bfv[2];
            #pragma unroll
            for (int mi = 0; mi < 2; ++mi) {
                int m = (mt_base + mi) * 16 + (l & 15);
                int c = t * 8 + s * 4 + (l >> 4);
                int slot = c ^ (l & 7);
                af[mi] = *(const short8*)(s_A + m * 128 + slot * 8);
            }
            #pragma unroll
            for (int ni = 0; ni < 2; ++ni)
                bfv[ni] = *(const short8*)(s_B + ((s * 4 + nt_base + ni) * 64 + l) * 8);
            #pragma unroll
            for (int mi = 0; mi < 2; ++mi)
                #pragma unroll
                for (int ni = 0; ni < 2; ++ni)
                    acc[mi][ni] = __builtin_amdgcn_mfma_f32_16x16x32_bf16(
                        af[mi], bfv[ni], acc[mi][ni], 0, 0, 0);
        }
    }
    #pragma unroll
    for (int mi = 0; mi < 2; ++mi) {
        #pragma unroll
        for (int ni = 0; ni < 2; ++ni) {
            int f = (nt_base + ni) * 16 + (l & 15);
            float bv = b[f];
            #pragma unroll
            for (int r = 0; r < 4; ++r) {
                int m = (mt_base + mi) * 16 + (l >> 4) * 4 + r;
                int gn = n0 + m;
                if (gn < NN)
                    out[(size_t)gn * IN_DIM + f] = gmask[gn] ? (acc[mi][ni][r] + bv) : 0.f;
            }
        }
    }
    if (tx < 192) {
        int i = tx / 3, c = tx % 3;
        int gn = n0 + i;
        if (gn < NN)
            out[(size_t)NN * IN_DIM + gn * 3 + c] = gmask[gn] ? x[gn * 3 + c] : 0.f;
    }
}

// ================= fallback path (atomic, scalar; used only if ws too small) =================
__global__ __launch_bounds__(256) void init_fb_kernel(
    const float* __restrict__ X_t, const int* __restrict__ edges,
    float* __restrict__ x, float* __restrict__ cnt)
{
    int gid = blockIdx.x * blockDim.x + threadIdx.x;
    int stride = gridDim.x * blockDim.x;
    for (int i = gid; i < NN * 3; i += stride) x[i] = X_t[i];
    for (int e = gid; e < NE; e += stride)
        atomicAdd(&cnt[edges[NE + e]], 1.0f);
}

__global__ __launch_bounds__(128) void node_mlp_kernel(
    const float* __restrict__ H_t, const float* __restrict__ cond,
    const float* __restrict__ t_in,
    const float* __restrict__ W0, const float* __restrict__ b0,
    const float* __restrict__ W1, const float* __restrict__ b1,
    const float* __restrict__ W2, const float* __restrict__ b2,
    float* __restrict__ h)
{
    __shared__ float s_feat[D0][20];
    __shared__ float s_h0[HID][20];
    __shared__ float s_h1[HID][20];
    int n0 = blockIdx.x * 16;
    int tx = threadIdx.x;

    for (int idx = tx; idx < 16 * IN_DIM; idx += 128) {
        int i = idx >> 6, k = idx & 63;
        s_feat[k][i] = H_t[(n0 + i) * IN_DIM + k];
    }
    for (int idx = tx; idx < 16 * HID; idx += 128) {
        int i = idx >> 7, k = idx & 127;
        s_feat[IN_DIM + k][i] = cond[(n0 + i) * HID + k];
    }
    const float cfr = -logf(10000.f) / 63.f;
    for (int idx = tx; idx < 16 * HID; idx += 128) {
        int i = idx >> 7, k = idx & 127;
        float tv = t_in[n0 + i];
        int jj = k & 63;
        float ang = tv * __expf(cfr * (float)jj);
        s_feat[IN_DIM + HID + k][i] = (k < 64) ? __sinf(ang) : __cosf(ang);
    }
    __syncthreads();

    float acc[16];
    {
        float bv = b0[tx];
        #pragma unroll
        for (int i = 0; i < 16; ++i) acc[i] = bv;
        for (int k = 0; k < D0; ++k) {
            float w = W0[k * HID + tx];
            float4 f0 = *(const float4*)&s_feat[k][0];
            float4 f1 = *(const float4*)&s_feat[k][4];
            float4 f2 = *(const float4*)&s_feat[k][8];
            float4 f3 = *(const float4*)&s_feat[k][12];
            acc[0] += f0.x*w; acc[1] += f0.y*w; acc[2] += f0.z*w; acc[3] += f0.w*w;
            acc[4] += f1.x*w; acc[5] += f1.y*w; acc[6] += f1.z*w; acc[7] += f1.w*w;
            acc[8] += f2.x*w; acc[9] += f2.y*w; acc[10]+= f2.z*w; acc[11]+= f2.w*w;
            acc[12]+= f3.x*w; acc[13]+= f3.y*w; acc[14]+= f3.z*w; acc[15]+= f3.w*w;
        }
        #pragma unroll
        for (int i = 0; i < 16; ++i) s_h0[tx][i] = fmaxf(acc[i], 0.f);
    }
    __syncthreads();
    {
        float bv = b1[tx];
        #pragma unroll
        for (int i = 0; i < 16; ++i) acc[i] = bv;
        for (int k = 0; k < HID; ++k) {
            float w = W1[k * HID + tx];
            float4 f0 = *(const float4*)&s_h0[k][0];
            float4 f1 = *(const float4*)&s_h0[k][4];
            float4 f2 = *(const float4*)&s_h0[k][8];
            float4 f3 = *(const float4*)&s_h0[k][12];
            acc[0] += f0.x*w; acc[1] += f0.y*w; acc[2] += f0.z*w; acc[3] += f0.w*w;
            acc[4] += f1.x*w; acc[5] += f1.y*w; acc[6] += f1.z*w; acc[7] += f1.w*w;
            acc[8] += f2.x*w; acc[9] += f2.y*w; acc[10]+= f2.z*w; acc[11]+= f2.w*w;
            acc[12]+= f3.x*w; acc[13]+= f3.y*w; acc[14]+= f3.z*w; acc[15]+= f3.w*w;
        }
        #pragma unroll
        for (int i = 0; i < 16; ++i) s_h1[tx][i] = fmaxf(acc[i], 0.f);
    }
    __syncthreads();
    {
        float bv = b2[tx];
        #pragma unroll
        for (int i = 0; i < 16; ++i) acc[i] = bv;
        for (int k = 0; k < HID; ++k) {
            float w = W2[k * HID + tx];
            float4 f0 = *(const float4*)&s_h1[k][0];
            float4 f1 = *(const float4*)&s_h1[k][4];
            float4 f2 = *(const float4*)&s_h1[k][8];
            float4 f3 = *(const float4*)&s_h1[k][12];
            acc[0] += f0.x*w; acc[1] += f0.y*w; acc[2] += f0.z*w; acc[3] += f0.w*w;
            acc[4] += f1.x*w; acc[5] += f1.y*w; acc[6] += f1.z*w; acc[7] += f1.w*w;
            acc[8] += f2.x*w; acc[9] += f2.y*w; acc[10]+= f2.z*w; acc[11]+= f2.w*w;
            acc[12]+= f3.x*w; acc[13]+= f3.y*w; acc[14]+= f3.z*w; acc[15]+= f3.w*w;
        }
        #pragma unroll
        for (int i = 0; i < 16; ++i) h[(n0 + i) * HID + tx] = acc[i];
    }
}

__global__ __launch_bounds__(256) void edge_gemm_fb_kernel(
    const float* __restrict__ h, const float* __restrict__ x,
    const int* __restrict__ edges, const int* __restrict__ etype,
    const float* __restrict__ edge_table,
    const float* __restrict__ We_l, const float* __restrict__ be_l,
    const float* __restrict__ Wx_l, const float* __restrict__ bx_l,
    float* __restrict__ agg_m, float* __restrict__ agg_x)
{
    __shared__ int s_src[TILE_E], s_dst[TILE_E];
    __shared__ float s_diff[TILE_E][3];
    __shared__ float s_tail[TILE_E][36];
    __shared__ float s_Af[TILE_E][36];
    __shared__ float s_Bf[33][HID];
    __shared__ float s_wx[HID];

    int e0 = blockIdx.x * TILE_E;
    int tx = threadIdx.x;
    int tf = tx & 15;
    int te = tx >> 4;

    if (tx < TILE_E) {
        int s = edges[e0 + tx];
        int d = edges[NE + e0 + tx];
        s_src[tx] = s; s_dst[tx] = d;
        float dx = x[s * 3 + 0] - x[d * 3 + 0];
        float dy = x[s * 3 + 1] - x[d * 3 + 1];
        float dz = x[s * 3 + 2] - x[d * 3 + 2];
        s_diff[tx][0] = dx; s_diff[tx][1] = dy; s_diff[tx][2] = dz;
        s_tail[tx][0] = dx * dx + dy * dy + dz * dz;
        int et = etype[e0 + tx];
        #pragma unroll
        for (int j = 0; j < 32; ++j) s_tail[tx][1 + j] = edge_table[et * 32 + j];
    }
    if (tx < HID) s_wx[tx] = Wx_l[tx];
    __syncthreads();

    float acc[4][8];
    #pragma unroll
    for (int i = 0; i < 4; ++i)
        #pragma unroll
        for (int j = 0; j < 8; ++j) acc[i][j] = 0.f;

    for (int t = 0; t < 9; ++t) {
        int k0 = t * 32;
        int klen = (t == 8) ? 33 : 32;
        __syncthreads();
        if (t < 8) {
            const bool use_src = (t < 4);
            int kbase = (t & 3) * 32;
            for (int q4 = tx; q4 < TILE_E * 8; q4 += 256) {
                int e = q4 >> 3, q = q4 & 7;
                int row = use_src ? s_src[e] : s_dst[e];
                float4 v = *(const float4*)&h[row * HID + kbase + q * 4];
                *(float4*)&s_Af[e][q * 4] = v;
            }
        }
        for (int q4 = tx; q4 < klen * 32; q4 += 256) {
            int kk = q4 >> 5, c4 = q4 & 31;
            float4 v = *(const float4*)&We_l[(k0 + kk) * HID + c4 * 4];
            *(float4*)&s_Bf[kk][c4 * 4] = v;
        }
        __syncthreads();
        const float (*Asrc)[36] = (t == 8) ? (const float (*)[36])s_tail
                                           : (const float (*)[36])s_Af;
        for (int kk = 0; kk < klen; ++kk) {
            float a0 = Asrc[te * 4 + 0][kk];
            float a1 = Asrc[te * 4 + 1][kk];
            float a2 = Asrc[te * 4 + 2][kk];
            float a3 = Asrc[te * 4 + 3][kk];
            float4 bv0 = *(const float4*)&s_Bf[kk][tf * 8];
            float4 bv1 = *(const float4*)&s_Bf[kk][tf * 8 + 4];
            float b[8] = {bv0.x, bv0.y, bv0.z, bv0.w, bv1.x, bv1.y, bv1.z, bv1.w};
            #pragma unroll
            for (int j = 0; j < 8; ++j) {
                acc[0][j] += a0 * b[j];
                acc[1][j] += a1 * b[j];
                acc[2][j] += a2 * b[j];
                acc[3][j] += a3 * b[j];
            }
        }
    }

    float wsum[4];
    #pragma unroll
    for (int i = 0; i < 4; ++i) {
        float p = 0.f;
        #pragma unroll
        for (int j = 0; j < 8; ++j) {
            int f = tf * 8 + j;
            float v = acc[i][j] + be_l[f];
            float m = silu(v);
            acc[i][j] = m;
            p += m * s_wx[f];
        }
        wsum[i] = p;
    }
    #pragma unroll
    for (int off = 1; off < 16; off <<= 1) {
        #pragma unroll
        for (int i = 0; i < 4; ++i) wsum[i] += __shfl_xor(wsum[i], off);
    }
    float bxv = bx_l[0];
    if (tf < 3) {
        #pragma unroll
        for (int i = 0; i < 4; ++i) {
            int e = te * 4 + i;
            float w2 = wsum[i] + bxv;
            atomicAdd(&agg_x[s_dst[e] * 3 + tf], s_diff[e][tf] * w2);
        }
    }
    #pragma unroll
    for (int i = 0; i < 4; ++i) {
        int d = s_dst[te * 4 + i];
        #pragma unroll
        for (int j = 0; j < 8; ++j)
            atomicAdd(&agg_m[d * HID + tf * 8 + j], acc[i][j]);
    }
}

__global__ __launch_bounds__(128) void node_update_fb_kernel(
    float* __restrict__ h, float* __restrict__ x,
    const float* __restrict__ agg_m, const float* __restrict__ agg_x,
    const float* __restrict__ cnt,
    const float* __restrict__ Wh_l, const float* __restrict__ bh_l)
{
    __shared__ float s_in[256][20];
    int n0 = blockIdx.x * 16;
    int tx = threadIdx.x;
    for (int idx = tx; idx < 16 * HID; idx += 128) {
        int i = idx >> 7, k = idx & 127;
        s_in[k][i] = h[(n0 + i) * HID + k];
    }
    for (int idx = tx; idx < 16 * HID; idx += 128) {
        int i = idx >> 7, k = idx & 127;
        s_in[HID + k][i] = agg_m[(n0 + i) * HID + k];
    }
    __syncthreads();
    float acc[16];
    float bv = bh_l[tx];
    #pragma unroll
    for (int i = 0; i < 16; ++i) acc[i] = bv;
    for (int k = 0; k < 256; ++k) {
        float w = Wh_l[k * HID + tx];
        float4 f0 = *(const float4*)&s_in[k][0];
        float4 f1 = *(const float4*)&s_in[k][4];
        float4 f2 = *(const float4*)&s_in[k][8];
        float4 f3 = *(const float4*)&s_in[k][12];
        acc[0] += f0.x*w; acc[1] += f0.y*w; acc[2] += f0.z*w; acc[3] += f0.w*w;
        acc[4] += f1.x*w; acc[5] += f1.y*w; acc[6] += f1.z*w; acc[7] += f1.w*w;
        acc[8] += f2.x*w; acc[9] += f2.y*w; acc[10]+= f2.z*w; acc[11]+= f2.w*w;
        acc[12]+= f3.x*w; acc[13]+= f3.y*w; acc[14]+= f3.z*w; acc[15]+= f3.w*w;
    }
    #pragma unroll
    for (int i = 0; i < 16; ++i) {
        float v = acc[i];
        h[(n0 + i) * HID + tx] = s_in[tx][i] + silu(v);
    }
    if (tx < 48) {
        int i = tx / 3, c = tx % 3;
        int n = n0 + i;
        x[n * 3 + c] += agg_x[n * 3 + c] / (cnt[n] + 1.f);
    }
}

__global__ __launch_bounds__(64) void final_fb_kernel(
    const float* __restrict__ h, const float* __restrict__ x,
    const int* __restrict__ gmask,
    const float* __restrict__ W, const float* __restrict__ b,
    float* __restrict__ out)
{
    __shared__ float s_h[8][HID];
    int n0 = blockIdx.x * 8;
    int tx = threadIdx.x;
    for (int idx = tx; idx < 8 * HID; idx += 64) {
        int i = idx >> 7, k = idx & 127;
        s_h[i][k] = h[(n0 + i) * HID + k];
    }
    __syncthreads();
    float acc[8];
    float bv = b[tx];
    #pragma unroll
    for (int i = 0; i < 8; ++i) acc[i] = bv;
    for (int k = 0; k < HID; ++k) {
        float w = W[k * IN_DIM + tx];
        #pragma unroll
        for (int i = 0; i < 8; ++i) acc[i] += s_h[i][k] * w;
    }
    #pragma unroll
    for (int i = 0; i < 8; ++i) {
        int n = n0 + i;
        out[n * IN_DIM + tx] = gmask[n] ? acc[i] : 0.f;
    }
    if (tx < 24) {
        int i = tx / 3, c = tx % 3;
        int n = n0 + i;
        out[NN * IN_DIM + n * 3 + c] = gmask[n] ? x[n * 3 + c] : 0.f;
    }
}

extern "C" void kernel_launch(void* const* d_in, const int* in_sizes, int n_in,
                              void* d_out, int out_size, void* d_ws, size_t ws_size,
                              hipStream_t stream) {
    const float* H_t   = (const float*)d_in[0];
    const float* X_t   = (const float*)d_in[1];
    const float* cond  = (const float*)d_in[2];
    const float* t_in  = (const float*)d_in[3];
    const int*   edges = (const int*)d_in[4];
    const int*   etype = (const int*)d_in[5];
    const int*   gmask = (const int*)d_in[6];
    const float* W0 = (const float*)d_in[8];
    const float* b0 = (const float*)d_in[9];
    const float* W1 = (const float*)d_in[10];
    const float* b1 = (const float*)d_in[11];
    const float* W2 = (const float*)d_in[12];
    const float* b2 = (const float*)d_in[13];
    const float* edge_table = (const float*)d_in[14];
    const float* We = (const float*)d_in[15];
    const float* be = (const float*)d_in[16];
    const float* Wx = (const float*)d_in[17];
    const float* bx = (const float*)d_in[18];
    const float* Wh = (const float*)d_in[19];
    const float* bh = (const float*)d_in[20];
    const float* h2i_W = (const float*)d_in[21];
    const float* h2i_b = (const float*)d_in[22];

    char* p = (char*)d_ws;
    float* h = (float*)p;           p += (size_t)NN * HID * 4;
    u16* h_bf = (u16*)p;            p += (size_t)NN * HID * 2;
    float* xa = (float*)p;          p += (size_t)NN * 3 * 4;
    float* xb = (float*)p;          p += (size_t)NN * 3 * 4;
    u16* Cbf = (u16*)p;             p += (size_t)NN * 256 * 2;
    u16* Bpack = (u16*)p;           p += (size_t)PACK_TOT * 2;
    float* tv = (float*)p;          p += (size_t)768 * 4;
    float* wed2 = (float*)p;        p += (size_t)384 * 4;
    int* row_start = (int*)p;       p += (size_t)(NN + 4) * 4;
    int* deg = (int*)p;             p += (size_t)NN * 4;
    int* head = (int*)p;            p += (size_t)NN * 4;
    int* src_s = (int*)p;           p += (size_t)NE * 4;
    size_t need = (size_t)(p - (char*)d_ws);

    if (ws_size >= need) {
        hipMemsetAsync(deg, 0, NN * sizeof(int), stream);
        hist_kernel<<<256, 256, 0, stream>>>(X_t, edges, xa, deg);
        scan_kernel<<<1, 1024, 0, stream>>>(deg, row_start, head);
        scatter_kernel<<<256, 256, 0, stream>>>(edges, etype, head, src_s);
        pack_all_kernel<<<(PACK_TOT + 255) / 256, 256, 0, stream>>>(
            We, W0, W1, W2, Wh, h2i_W, Bpack);
        precomp_tv_kernel<<<5, 256, 0, stream>>>(edge_table, We, be, tv, wed2);
        node_mlp_mfma_kernel<<<NB64, 256, 0, stream>>>(
            H_t, cond, t_in,
            Bpack + OFF_W0, b0, Bpack + OFF_W1, b1, Bpack + OFF_W2, b2,
            Bpack + OFF_WE, Cbf,
            h, h_bf);
        for (int l = 0; l < 3; ++l) {
            if (l > 0)
                cvec_kernel<<<NB64, 256, 0, stream>>>(
                    h_bf, Bpack + OFF_WE + (size_t)l * 40960, Cbf);
            const float* xin = (l & 1) ? xb : xa;
            float* xout = (l & 1) ? xa : xb;
            node_fused_kernel<<<NN / NUB, 512, 0, stream>>>(
                h, h_bf, xin, xout, Cbf, src_s, row_start,
                tv + (size_t)l * 256, wed2 + (size_t)l * 128,
                Wx + l * HID, bx + l,
                Bpack + OFF_WH + (size_t)l * 32768, bh + l * HID);
        }
        // layers: l0 xa->xb, l1 xb->xa, l2 xa->xb  => final x lives in xb
        final_mfma_kernel<<<NB64, 256, 0, stream>>>(
            h_bf, xb, gmask, Bpack + OFF_H2I, h2i_b, (float*)d_out);
    } else {
        // fallback: scalar atomic path (~21 MB)
        float* ws    = (float*)d_ws;
        float* fh    = ws;
        float* fx    = fh + NN * HID;
        float* cnt   = fx + NN * 3;
        float* fagg_m = cnt + NN;
        float* fagg_x = fagg_m + NN * HID;

        hipMemsetAsync(cnt, 0, NN * sizeof(float), stream);
        init_fb_kernel<<<256, 256, 0, stream>>>(X_t, edges, fx, cnt);
        node_mlp_kernel<<<NN / 16, 128, 0, stream>>>(H_t, cond, t_in,
                                                     W0, b0, W1, b1, W2, b2, fh);
        for (int l = 0; l < 3; ++l) {
            hipMemsetAsync(fagg_m, 0, (size_t)NN * 131 * sizeof(float), stream);
            edge_gemm_fb_kernel<<<NE / TILE_E, 256, 0, stream>>>(
                fh, fx, edges, etype, edge_table,
                We + (size_t)l * DE * HID, be + l * HID,
                Wx + l * HID, bx + l, fagg_m, fagg_x);
            node_update_fb_kernel<<<NN / 16, 128, 0, stream>>>(
                fh, fx, fagg_m, fagg_x, cnt,
                Wh + (size_t)l * 256 * HID, bh + l * HID);
        }
        final_fb_kernel<<<NN / 8, 64, 0, stream>>>(fh, fx, gmask, h2i_W, h2i_b, (float*)d_out);
    }
}